// Round 12
// baseline (614.567 us; speedup 1.0000x reference)
//
#include <hip/hip_runtime.h>

// GCN(3 layers) + MLP(4 layers), N=50000, E=800000, out = N x 8 bf16.
// NOTE: do NOT include <hip/hip_bf16.h> — breaks this harness's build
// (rounds 1-4 fell back to a stub; round 5 proved it). Manual bf16 ushort ops.
// Dtype runtime-detection: flagI (edge_index int64 vs int32), flagF (floats
// fp32 vs packed bf16).
//
// R12: CSR build via 2-level binning (bucket = 32 consecutive dst nodes).
// R11's fill was the top dispatch: 800k random 4B scatters -> 52.7 MB
// line-amplified writes at ~1 TB/s (55us) + count_indeg random atomics.
// New chain: bcount (1563 L2-hot counters) -> bscan -> bin (append int2
// pairs, consecutive addresses = full-line writes) -> bucket (block per
// bucket: LDS count/prefix/place into contiguous CSR slice; also emits
// indeg/offsets/dinv). Replaces count+scan1/2/3+fill.

#define GN 50000
#define GE 800000
#define NPB 32                       // nodes per bucket
#define NBKT ((GN + NPB - 1) / NPB)  // 1563

typedef __attribute__((ext_vector_type(8))) short bf16x8;
typedef __attribute__((ext_vector_type(4))) float floatx4;

__device__ __forceinline__ float ar1_b2f(unsigned short h) {
    return __uint_as_float(((unsigned)h) << 16);
}
__device__ __forceinline__ unsigned short ar1_f2b(float f) {
    unsigned u = __float_as_uint(f);
    u = u + 0x7FFFu + ((u >> 16) & 1u);   // round-to-nearest-even
    return (unsigned short)(u >> 16);
}

__global__ void ar1_zero(int* p, int n) {
    int i = blockIdx.x * 256 + threadIdx.x;
    if (i < n) p[i] = 0;
}

// flagI[0]=1 => edge_index is int64
__global__ void ar1_detect_idx(const int* ei, int* flagI) {
    __shared__ int cnt;
    if (threadIdx.x == 0) cnt = 0;
    __syncthreads();
    if (ei[2 * threadIdx.x + 1] != 0) atomicAdd(&cnt, 1);
    __syncthreads();
    if (threadIdx.x == 0) flagI[0] = (cnt < 8) ? 1 : 0;
}

// flagF[0]=1 => float tensors are fp32; 0 => packed bf16 (see R6 notes).
__global__ void ar1_detect_f(const unsigned short* xw, int* flagF) {
    __shared__ int cnt;
    if (threadIdx.x == 0) cnt = 0;
    __syncthreads();
    unsigned short w = xw[2 * threadIdx.x];
    int ex = (w >> 7) & 0xFF;
    if (w == 0 || (ex >= 90 && ex <= 150)) atomicAdd(&cnt, 1);
    __syncthreads();
    if (threadIdx.x == 0) flagF[0] = (cnt > 200) ? 0 : 1;
}

// ---- graph build: 2-level binning ----
__global__ void ar1_bcount(const int* ei, const int* flagI, int* bcnt, int E) {
    int e = blockIdx.x * 256 + threadIdx.x;
    if (e < E) {
        int d = flagI[0] ? ei[2 * (E + e)] : ei[E + e];
        if ((unsigned)d < (unsigned)GN) atomicAdd(&bcnt[d >> 5], 1);
    }
}

// single-block exclusive scan of bucket counts -> bstart, bcursor
__global__ void ar1_bscan(const int* bcnt, int* bstart, int* bcursor, int nb) {
    __shared__ int sm[256];
    __shared__ int carry;
    int tid = threadIdx.x;
    if (tid == 0) carry = 0;
    __syncthreads();
    for (int base = 0; base < nb; base += 256) {
        int i = base + tid;
        int v = (i < nb) ? bcnt[i] : 0;
        sm[tid] = v;
        __syncthreads();
        for (int off = 1; off < 256; off <<= 1) {
            int t = (tid >= off) ? sm[tid - off] : 0;
            __syncthreads();
            sm[tid] += t;
            __syncthreads();
        }
        if (i < nb) {
            int excl = sm[tid] - v + carry;
            bstart[i] = excl;
            bcursor[i] = excl;
        }
        __syncthreads();
        if (tid == 0) carry += sm[255];
        __syncthreads();
    }
    if (tid == 0) bstart[nb] = carry;
}

// append (s,d) pairs into bucket regions (consecutive addresses per bucket)
__global__ void ar1_bin(const int* ei, const int* flagI, int* bcursor,
                        int2* pairs, int E) {
    int e = blockIdx.x * 256 + threadIdx.x;
    if (e < E) {
        int is64 = flagI[0];
        int s = is64 ? ei[2 * e] : ei[e];
        int d = is64 ? ei[2 * (E + e)] : ei[E + e];
        if ((unsigned)s < (unsigned)GN && (unsigned)d < (unsigned)GN) {
            int p = atomicAdd(&bcursor[d >> 5], 1);
            pairs[p] = make_int2(s, d);
        }
    }
}

// per-bucket: LDS count -> prefix -> place into contiguous CSR slice;
// emits indeg/offsets/dinv for the bucket's 32 nodes.
__global__ void ar1_bucket(const int2* pairs, const int* bstart,
                           int* csr, int* indeg, int* offs, float* dinv) {
    __shared__ int cnt[NPB], pre[NPB], cur[NPB];
    int b = (int)blockIdx.x;
    int tid = (int)threadIdx.x;
    int base = bstart[b], end = bstart[b + 1];
    int sz = end - base;
    if (tid < NPB) cnt[tid] = 0;
    __syncthreads();
    for (int i = tid; i < sz; i += 256)
        atomicAdd(&cnt[pairs[base + i].y & (NPB - 1)], 1);
    __syncthreads();
    if (tid == 0) {
        int s = 0;
        for (int j = 0; j < NPB; j++) { pre[j] = s; s += cnt[j]; }
    }
    __syncthreads();
    if (tid < NPB) {
        cur[tid] = pre[tid];
        int node = b * NPB + tid;
        if (node < GN) {
            indeg[node] = cnt[tid];
            offs[node] = base + pre[tid];
            dinv[node] = rsqrtf((float)(cnt[tid] + 1));   // +1: self loop
        }
    }
    __syncthreads();
    for (int i = tid; i < sz; i += 256) {
        int2 pr = pairs[base + i];
        int p = atomicAdd(&cur[pr.y & (NPB - 1)], 1);
        csr[base + p] = pr.x;
    }
}

// fused small-vector -> fp32 conversion (biases, gamma, beta)
struct SmallCvt {
    const void* src[13];
    float* dst[13];
    int n[13];
};
__global__ void ar1_cvt_small(SmallCvt sc, const int* flagF) {
    int f = flagF[0];
    for (int s = 0; s < 13; s++) {
        for (int i = threadIdx.x; i < sc.n[s]; i += 256) {
            float v = f ? ((const float*)sc.src[s])[i]
                        : ar1_b2f(((const unsigned short*)sc.src[s])[i]);
            sc.dst[s][i] = v;
        }
    }
}

// fused pack of all 7 weights into MFMA B-fragment order:
// Bp[(frag*64+lane)*8+j] = bf16(W[(c*32+(lane>>4)*8+j)*M + t*16+(lane&15)]),
// frag = t*(K/32)+c; n >= M reads as 0 (lw4 M=8 padding).
struct PackAll {
    const void* src[7];
    unsigned short* dst[7];
    int K[7], M[7], start[8];
};
__global__ void ar1_pack_all(PackAll pa, const int* flagF) {
    int b = (int)blockIdx.x;
    int w = 0;
    while (w < 6 && b >= pa.start[w + 1]) w++;
    int frag = b - pa.start[w];
    int K = pa.K[w], M = pa.M[w];
    int lane = (int)threadIdx.x;
    int nch = K >> 5;
    int t = frag / nch, c = frag - t * nch;
    int n = t * 16 + (lane & 15);
    int k0 = c * 32 + (lane >> 4) * 8;
    int f = flagF[0];
    unsigned short* o = pa.dst[w] + ((size_t)frag * 64 + lane) * 8;
    for (int j = 0; j < 8; j++) {
        unsigned short v = 0;
        if (n < M) {
            int idx = (k0 + j) * M + n;
            v = f ? ar1_f2b(((const float*)pa.src[w])[idx])
                  : ((const unsigned short*)pa.src[w])[idx];
        }
        o[j] = v;
    }
}

// ---------------- MFMA GEMM: C[GN,Mout] = A[GN,K] @ W[K,M] (+bias)(+relu) ---
// A bf16 rows of Astride; C rows of Cstride (bf16, or fp32 if f32out&&*f32out).
// Bp packed fragments; fp32 accum; NT*16 = padded M; K mult of 32.
template <int NT>
__global__ __launch_bounds__(256, 2)
void ar1_mfma(const unsigned short* __restrict__ A,
              const unsigned short* __restrict__ Bp,
              const float* __restrict__ bias,
              void* __restrict__ C, int K, int Astride, int Cstride,
              int Mout, int relu, const int* f32out) {
    int tid = (int)threadIdx.x;
    int wv = tid >> 6, lane = tid & 63;
    int mb = ((int)blockIdx.x * 4 + wv) * 16;
    int m = lane & 15, quad = lane >> 4;
    int arow = mb + m;
    if (arow >= GN) arow = GN - 1;          // clamp; rows >= GN never stored
    const unsigned short* Aptr = A + (size_t)arow * Astride + quad * 8;
    int nch = K >> 5;

    floatx4 acc[NT];
#pragma unroll
    for (int t = 0; t < NT; t++) acc[t] = (floatx4){0.f, 0.f, 0.f, 0.f};

    for (int c = 0; c < nch; c++) {
        bf16x8 a = *((const bf16x8*)(Aptr + c * 32));
#pragma unroll
        for (int t = 0; t < NT; t++) {
            bf16x8 b = *((const bf16x8*)(Bp + ((size_t)(t * nch + c) * 64 + lane) * 8));
            acc[t] = __builtin_amdgcn_mfma_f32_16x16x32_bf16(a, b, acc[t], 0, 0, 0);
        }
    }

    int wf32 = (f32out != (const int*)0) ? f32out[0] : 0;
#pragma unroll
    for (int t = 0; t < NT; t++) {
#pragma unroll
        for (int r = 0; r < 4; r++) {
            int row = mb + quad * 4 + r;
            int col = t * 16 + m;
            if (row < GN && col < Mout) {
                float v = acc[t][r];
                if (bias) v += bias[col];
                if (relu) v = fmaxf(v, 0.f);
                if (wf32) ((float*)C)[(size_t)row * Cstride + col] = v;
                else ((unsigned short*)C)[(size_t)row * Cstride + col] = ar1_f2b(v);
            }
        }
    }
}

// ---------------- GCN aggregate v2 ------------------------------------------
// H rows padded to 128 bf16 (256 B). Wave per node: lane = eslot(2b) x chunk
// (4b); per iteration gathers 4 edge rows x 16B; fp32 acc x8/lane; shfl_xor
// reduce over eslots; fused self-loop + bias + BN(eval) + ReLU. 4 nodes/blk.
__global__ __launch_bounds__(256, 4)
void ar1_agg2(const unsigned short* __restrict__ H, const int* __restrict__ offs,
              const int* __restrict__ indeg, const int* __restrict__ csr,
              const float* __restrict__ dinv,
              const float* __restrict__ bias, const float* __restrict__ gamma,
              const float* __restrict__ beta, unsigned short* __restrict__ Out) {
    int wv = (int)threadIdx.x >> 6, lane = (int)threadIdx.x & 63;
    int node = (int)blockIdx.x * 4 + wv;
    if (node >= GN) return;
    int chunk = lane & 15;     // feature chunk: feats chunk*8 .. +8
    int eslot = lane >> 4;     // 0..3
    float di = dinv[node];
    int off = offs[node], cnt = indeg[node];

    float acc[8];
#pragma unroll
    for (int j = 0; j < 8; j++) acc[j] = 0.f;

    for (int base = 0; base < cnt; base += 4) {
        int e = base + eslot;
        int s = node;
        float w = 0.f;
        if (e < cnt) {
            s = csr[off + e];
            if ((unsigned)s >= (unsigned)GN) s = node;
            w = dinv[s] * di;
        }
        bf16x8 h = *((const bf16x8*)(H + (size_t)s * 128 + chunk * 8));
#pragma unroll
        for (int j = 0; j < 8; j++)
            acc[j] += w * ar1_b2f((unsigned short)h[j]);
    }

    // reduce partial sums across the 4 edge-slot groups
#pragma unroll
    for (int j = 0; j < 8; j++) {
        acc[j] += __shfl_xor(acc[j], 16, 64);
        acc[j] += __shfl_xor(acc[j], 32, 64);
    }

    if (eslot == 0 && chunk < 12) {
        bf16x8 hs = *((const bf16x8*)(H + (size_t)node * 128 + chunk * 8));
#pragma unroll
        for (int j = 0; j < 8; j++) {
            int f = chunk * 8 + j;
            float v = acc[j] + di * di * ar1_b2f((unsigned short)hs[j]) + bias[f];
            v = v * 0.9999950000374997f * gamma[f] + beta[f];   // 1/sqrt(1+1e-5)
            Out[(size_t)node * 128 + f] = ar1_f2b(fmaxf(v, 0.f));
        }
    }
}

// x -> bf16 row-major (also carries the harness kernel name)
__global__ void Arthur1_16458314678864_kernel(const void* src,
                                              unsigned short* dst, int n,
                                              const int* flagF) {
    int i = blockIdx.x * 256 + threadIdx.x;
    if (i < n) {
        if (flagF[0]) dst[i] = ar1_f2b(((const float*)src)[i]);
        else          dst[i] = ((const unsigned short*)src)[i];
    }
}

extern "C" void kernel_launch(void* const* d_in, const int* in_sizes, int n_in,
                              void* d_out, int out_size, void* d_ws, size_t ws_size,
                              hipStream_t stream) {
    (void)in_sizes; (void)n_in; (void)out_size;

    // workspace layout
    char* p = (char*)d_ws;
    unsigned short* bufB = (unsigned short*)p; p += (size_t)GN * 256 * 2;  // 25.6 MB
    unsigned short* bufA = (unsigned short*)p; p += (size_t)GN * 128 * 2;  // 12.8 MB
    unsigned short* bufX = (unsigned short*)p; p += (size_t)GN * 64 * 2;   // 6.4 MB
    int2* pairs = (int2*)p;   p += (size_t)GE * 8;                         // 6.4 MB
    int* indeg  = (int*)p;    p += (size_t)GN * 4;
    int* offs   = (int*)p;    p += (size_t)GN * 4;
    float* dinv = (float*)p;  p += (size_t)GN * 4;
    int* csr    = (int*)p;    p += (size_t)GE * 4;                         // 3.2 MB
    int* bcnt   = (int*)p;    p += (NBKT + 1) * 4;
    int* bstart = (int*)p;    p += (NBKT + 1) * 4;
    int* bcursor= (int*)p;    p += (NBKT + 1) * 4;
    int* flagI  = (int*)p;    p += 1024;
    int* flagF  = (int*)p;    p += 1024;
    unsigned short* bpArena = (unsigned short*)p; p += 91136 * 2;  // packed W
    float* fArena = (float*)p; p += 2048 * 4;                      // small fp32
    size_t need = (size_t)(p - (char*)d_ws);
    if (ws_size < need) {
        hipMemsetAsync(d_out, 0x41, (size_t)GN * 8 * 2, stream);  // marker 12.06
        return;
    }

    // packed-weight arena offsets (shorts): w1,w2,w3,lw1,lw2,lw3,lw4
    unsigned short* bp[7];
    int bpn[7] = {6144, 9216, 9216, 24576, 32768, 8192, 1024};
    {
        unsigned short* q = bpArena;
        for (int i = 0; i < 7; i++) { bp[i] = q; q += bpn[i]; }
    }

    // small fp32 arena: b1,g1,be1,b2,g2,be2,b3,g3,be3, lb1,lb2,lb3,lb4
    float* fs[13];
    int fn[13] = {96,96,96, 96,96,96, 96,96,96, 256,128,64,8};
    int fsrc[13] = {3,4,5, 7,8,9, 11,12,13, 15,17,19,21};
    {
        float* q = fArena;
        for (int i = 0; i < 13; i++) { fs[i] = q; q += fn[i]; }
    }

    const int* ei = (const int*)d_in[1];
    const int EB = (GE + 255) / 256;

    ar1_detect_idx<<<1, 256, 0, stream>>>(ei, flagI);
    ar1_detect_f<<<1, 256, 0, stream>>>((const unsigned short*)d_in[0], flagF);

    // graph build (binned)
    ar1_zero<<<(NBKT + 255) / 256, 256, 0, stream>>>(bcnt, NBKT);
    ar1_bcount<<<EB, 256, 0, stream>>>(ei, flagI, bcnt, GE);
    ar1_bscan<<<1, 256, 0, stream>>>(bcnt, bstart, bcursor, NBKT);
    ar1_bin<<<EB, 256, 0, stream>>>(ei, flagI, bcursor, pairs, GE);
    ar1_bucket<<<NBKT, 256, 0, stream>>>(pairs, bstart, csr, indeg, offs, dinv);

    // conversions
    Arthur1_16458314678864_kernel<<<(GN * 64 + 255) / 256, 256, 0, stream>>>(
        d_in[0], bufX, GN * 64, flagF);
    {
        SmallCvt sc;
        for (int i = 0; i < 13; i++) { sc.src[i] = d_in[fsrc[i]]; sc.dst[i] = fs[i]; sc.n[i] = fn[i]; }
        ar1_cvt_small<<<1, 256, 0, stream>>>(sc, flagF);
    }
    {
        PackAll pa;
        int wsrc[7] = {2, 6, 10, 14, 16, 18, 20};
        int Ks[7] = {64, 96, 96, 96, 256, 128, 64};
        int Ms[7] = {96, 96, 96, 256, 128, 64, 8};
        int cum = 0;
        for (int i = 0; i < 7; i++) {
            pa.src[i] = d_in[wsrc[i]]; pa.dst[i] = bp[i];
            pa.K[i] = Ks[i]; pa.M[i] = Ms[i];
            pa.start[i] = cum;
            cum += (Ms[i] + 15) / 16 * (Ks[i] / 32);
        }
        pa.start[7] = cum;   // 178
        ar1_pack_all<<<cum, 64, 0, stream>>>(pa, flagF);
    }

    const int GB = (GN + 63) / 64;    // 64 rows per block (4 waves x 16)
    const int AB = GN / 4;            // agg2: 4 nodes per block (12500 exact)

    // GCN 1..3 (A stride / C stride 128-padded; bias/BN/ReLU fused in agg)
    ar1_mfma<6><<<GB, 256, 0, stream>>>(bufX, bp[0], (const float*)0, bufB, 64, 64, 128, 96, 0, (const int*)0);
    ar1_agg2<<<AB, 256, 0, stream>>>(bufB, offs, indeg, csr, dinv, fs[0], fs[1], fs[2], bufA);
    ar1_mfma<6><<<GB, 256, 0, stream>>>(bufA, bp[1], (const float*)0, bufB, 96, 128, 128, 96, 0, (const int*)0);
    ar1_agg2<<<AB, 256, 0, stream>>>(bufB, offs, indeg, csr, dinv, fs[3], fs[4], fs[5], bufA);
    ar1_mfma<6><<<GB, 256, 0, stream>>>(bufA, bp[2], (const float*)0, bufB, 96, 128, 128, 96, 0, (const int*)0);
    ar1_agg2<<<AB, 256, 0, stream>>>(bufB, offs, indeg, csr, dinv, fs[6], fs[7], fs[8], bufA);

    // MLP: 96->256->128->64->8 (last layer writes d_out, fp32/bf16 per flagF)
    ar1_mfma<16><<<GB, 256, 0, stream>>>(bufA, bp[3], fs[9],  bufB, 96, 128, 256, 256, 1, (const int*)0);
    ar1_mfma<8><<<GB, 256, 0, stream>>>(bufB, bp[4], fs[10], bufA, 256, 256, 128, 128, 1, (const int*)0);
    ar1_mfma<4><<<GB, 256, 0, stream>>>(bufA, bp[5], fs[11], bufB, 128, 128, 64, 64, 1, (const int*)0);
    ar1_mfma<1><<<GB, 256, 0, stream>>>(bufB, bp[6], fs[12], d_out, 64, 64, 8, 8, 0, flagF);
}

// Round 13
// 441.709 us; speedup vs baseline: 1.3913x; 1.3913x over previous
//
#include <hip/hip_runtime.h>

// GCN(3 layers) + MLP(4 layers), N=50000, E=800000, out = N x 8 bf16.
// NOTE: do NOT include <hip/hip_bf16.h> — breaks this harness's build
// (rounds 1-4 fell back to a stub; round 5 proved it). Manual bf16 ushort ops.
// Dtype runtime-detection: flagI (edge_index int64 vs int32), flagF (floats
// fp32 vs packed bf16).
//
// R13: (a) graph build reverted to R11 chain — R12's 1563-bucket binning
// serialized on cursor atomics (512 atomics/cursor, 122us vs fill's 55us;
// write amplification unchanged). 50k cursors = low contention wins.
// (b) agg3: 2x edge unroll (two independent gather chains/lane) + 8 waves/EU
// — agg2 was latency-bound (~45us, FETCH ~8 XCD x 12.8 MB structural).
// (c) detect_idx+detect_f fused into one 2-block kernel.

#define GN 50000
#define GE 800000

typedef __attribute__((ext_vector_type(8))) short bf16x8;
typedef __attribute__((ext_vector_type(4))) float floatx4;

__device__ __forceinline__ float ar1_b2f(unsigned short h) {
    return __uint_as_float(((unsigned)h) << 16);
}
__device__ __forceinline__ unsigned short ar1_f2b(float f) {
    unsigned u = __float_as_uint(f);
    u = u + 0x7FFFu + ((u >> 16) & 1u);   // round-to-nearest-even
    return (unsigned short)(u >> 16);
}

__global__ void ar1_zero(int* p, int n) {
    int i = blockIdx.x * 256 + threadIdx.x;
    if (i < n) p[i] = 0;
}

// block 0: flagI (edge_index int64 <=> odd words ~all zero)
// block 1: flagF (floats fp32 vs packed bf16; see R6 notes)
__global__ void ar1_detect(const int* ei, const unsigned short* xw,
                           int* flagI, int* flagF) {
    __shared__ int cnt;
    if (threadIdx.x == 0) cnt = 0;
    __syncthreads();
    if (blockIdx.x == 0) {
        if (ei[2 * threadIdx.x + 1] != 0) atomicAdd(&cnt, 1);
        __syncthreads();
        if (threadIdx.x == 0) flagI[0] = (cnt < 8) ? 1 : 0;
    } else {
        unsigned short w = xw[2 * threadIdx.x];
        int ex = (w >> 7) & 0xFF;
        if (w == 0 || (ex >= 90 && ex <= 150)) atomicAdd(&cnt, 1);
        __syncthreads();
        if (threadIdx.x == 0) flagF[0] = (cnt > 200) ? 0 : 1;
    }
}

__global__ void ar1_count(const int* ei, const int* flagI, int* indeg, int E) {
    int e = blockIdx.x * 256 + threadIdx.x;
    if (e < E) {
        int d = flagI[0] ? ei[2 * (E + e)] : ei[E + e];
        if ((unsigned)d < (unsigned)GN) atomicAdd(&indeg[d], 1);
    }
}

__global__ void ar1_scan1(const int* indeg, int* offsets, int* blksum, int n) {
    __shared__ int sm[256];
    int tid = threadIdx.x;
    int i = blockIdx.x * 256 + tid;
    int v = (i < n) ? indeg[i] : 0;
    sm[tid] = v;
    __syncthreads();
    for (int off = 1; off < 256; off <<= 1) {
        int t = (tid >= off) ? sm[tid - off] : 0;
        __syncthreads();
        sm[tid] += t;
        __syncthreads();
    }
    if (i < n) offsets[i] = sm[tid] - v;
    if (tid == 255) blksum[blockIdx.x] = sm[255];
}

__global__ void ar1_scan2(const int* blksum, int* blkbase, int nb) {
    __shared__ int sm[256];
    int tid = threadIdx.x;
    int v = (tid < nb) ? blksum[tid] : 0;
    sm[tid] = v;
    __syncthreads();
    for (int off = 1; off < 256; off <<= 1) {
        int t = (tid >= off) ? sm[tid - off] : 0;
        __syncthreads();
        sm[tid] += t;
        __syncthreads();
    }
    if (tid < nb) blkbase[tid] = sm[tid] - v;
}

__global__ void ar1_scan3(const int* indeg, int* offsets, int* cursor,
                          const int* blkbase, float* dinv, int n) {
    int i = blockIdx.x * 256 + threadIdx.x;
    if (i < n) {
        int o = offsets[i] + blkbase[blockIdx.x];
        offsets[i] = o;
        cursor[i] = o;
        dinv[i] = rsqrtf((float)(indeg[i] + 1));   // +1: self loop
    }
}

__global__ void ar1_fill(const int* ei, const int* flagI, int* cursor,
                         int* csr, int E) {
    int e = blockIdx.x * 256 + threadIdx.x;
    if (e < E) {
        int is64 = flagI[0];
        int s = is64 ? ei[2 * e] : ei[e];
        int d = is64 ? ei[2 * (E + e)] : ei[E + e];
        if ((unsigned)s < (unsigned)GN && (unsigned)d < (unsigned)GN) {
            int p = atomicAdd(&cursor[d], 1);
            csr[p] = s;
        }
    }
}

// fused small-vector -> fp32 conversion (biases, gamma, beta)
struct SmallCvt {
    const void* src[13];
    float* dst[13];
    int n[13];
};
__global__ void ar1_cvt_small(SmallCvt sc, const int* flagF) {
    int f = flagF[0];
    for (int s = 0; s < 13; s++) {
        for (int i = threadIdx.x; i < sc.n[s]; i += 256) {
            float v = f ? ((const float*)sc.src[s])[i]
                        : ar1_b2f(((const unsigned short*)sc.src[s])[i]);
            sc.dst[s][i] = v;
        }
    }
}

// fused pack of all 7 weights into MFMA B-fragment order:
// Bp[(frag*64+lane)*8+j] = bf16(W[(c*32+(lane>>4)*8+j)*M + t*16+(lane&15)]),
// frag = t*(K/32)+c; n >= M reads as 0 (lw4 M=8 padding).
struct PackAll {
    const void* src[7];
    unsigned short* dst[7];
    int K[7], M[7], start[8];
};
__global__ void ar1_pack_all(PackAll pa, const int* flagF) {
    int b = (int)blockIdx.x;
    int w = 0;
    while (w < 6 && b >= pa.start[w + 1]) w++;
    int frag = b - pa.start[w];
    int K = pa.K[w], M = pa.M[w];
    int lane = (int)threadIdx.x;
    int nch = K >> 5;
    int t = frag / nch, c = frag - t * nch;
    int n = t * 16 + (lane & 15);
    int k0 = c * 32 + (lane >> 4) * 8;
    int f = flagF[0];
    unsigned short* o = pa.dst[w] + ((size_t)frag * 64 + lane) * 8;
    for (int j = 0; j < 8; j++) {
        unsigned short v = 0;
        if (n < M) {
            int idx = (k0 + j) * M + n;
            v = f ? ar1_f2b(((const float*)pa.src[w])[idx])
                  : ((const unsigned short*)pa.src[w])[idx];
        }
        o[j] = v;
    }
}

// ---------------- MFMA GEMM: C[GN,Mout] = A[GN,K] @ W[K,M] (+bias)(+relu) ---
// A bf16 rows of Astride; C rows of Cstride (bf16, or fp32 if f32out&&*f32out).
// Bp packed fragments; fp32 accum; NT*16 = padded M; K mult of 32.
template <int NT>
__global__ __launch_bounds__(256, 2)
void ar1_mfma(const unsigned short* __restrict__ A,
              const unsigned short* __restrict__ Bp,
              const float* __restrict__ bias,
              void* __restrict__ C, int K, int Astride, int Cstride,
              int Mout, int relu, const int* f32out) {
    int tid = (int)threadIdx.x;
    int wv = tid >> 6, lane = tid & 63;
    int mb = ((int)blockIdx.x * 4 + wv) * 16;
    int m = lane & 15, quad = lane >> 4;
    int arow = mb + m;
    if (arow >= GN) arow = GN - 1;          // clamp; rows >= GN never stored
    const unsigned short* Aptr = A + (size_t)arow * Astride + quad * 8;
    int nch = K >> 5;

    floatx4 acc[NT];
#pragma unroll
    for (int t = 0; t < NT; t++) acc[t] = (floatx4){0.f, 0.f, 0.f, 0.f};

    for (int c = 0; c < nch; c++) {
        bf16x8 a = *((const bf16x8*)(Aptr + c * 32));
#pragma unroll
        for (int t = 0; t < NT; t++) {
            bf16x8 b = *((const bf16x8*)(Bp + ((size_t)(t * nch + c) * 64 + lane) * 8));
            acc[t] = __builtin_amdgcn_mfma_f32_16x16x32_bf16(a, b, acc[t], 0, 0, 0);
        }
    }

    int wf32 = (f32out != (const int*)0) ? f32out[0] : 0;
#pragma unroll
    for (int t = 0; t < NT; t++) {
#pragma unroll
        for (int r = 0; r < 4; r++) {
            int row = mb + quad * 4 + r;
            int col = t * 16 + m;
            if (row < GN && col < Mout) {
                float v = acc[t][r];
                if (bias) v += bias[col];
                if (relu) v = fmaxf(v, 0.f);
                if (wf32) ((float*)C)[(size_t)row * Cstride + col] = v;
                else ((unsigned short*)C)[(size_t)row * Cstride + col] = ar1_f2b(v);
            }
        }
    }
}

// ---------------- GCN aggregate v3 ------------------------------------------
// H rows padded to 128 bf16 (256 B). Wave per node: lane = eslot(2b) x chunk
// (4b). 2x edge unroll: two independent gather chains in flight per lane.
// fp32 acc x8/lane; shfl_xor reduce; fused self-loop+bias+BN+ReLU. 4 nodes/blk.
__global__ __launch_bounds__(256, 8)
void ar1_agg3(const unsigned short* __restrict__ H, const int* __restrict__ offs,
              const int* __restrict__ indeg, const int* __restrict__ csr,
              const float* __restrict__ dinv,
              const float* __restrict__ bias, const float* __restrict__ gamma,
              const float* __restrict__ beta, unsigned short* __restrict__ Out) {
    int wv = (int)threadIdx.x >> 6, lane = (int)threadIdx.x & 63;
    int node = (int)blockIdx.x * 4 + wv;
    if (node >= GN) return;
    int chunk = lane & 15;     // feature chunk: feats chunk*8 .. +8
    int eslot = lane >> 4;     // 0..3
    float di = dinv[node];
    int off = offs[node], cnt = indeg[node];

    float acc[8];
#pragma unroll
    for (int j = 0; j < 8; j++) acc[j] = 0.f;

    for (int base = 0; base < cnt; base += 8) {
        int e0 = base + eslot, e1 = base + 4 + eslot;
        int s0 = node, s1 = node;
        float w0 = 0.f, w1 = 0.f;
        if (e0 < cnt) {
            s0 = csr[off + e0];
            if ((unsigned)s0 >= (unsigned)GN) s0 = node;
            w0 = dinv[s0] * di;
        }
        if (e1 < cnt) {
            s1 = csr[off + e1];
            if ((unsigned)s1 >= (unsigned)GN) s1 = node;
            w1 = dinv[s1] * di;
        }
        bf16x8 h0 = *((const bf16x8*)(H + (size_t)s0 * 128 + chunk * 8));
        bf16x8 h1 = *((const bf16x8*)(H + (size_t)s1 * 128 + chunk * 8));
#pragma unroll
        for (int j = 0; j < 8; j++)
            acc[j] += w0 * ar1_b2f((unsigned short)h0[j])
                    + w1 * ar1_b2f((unsigned short)h1[j]);
    }

    // reduce partial sums across the 4 edge-slot groups
#pragma unroll
    for (int j = 0; j < 8; j++) {
        acc[j] += __shfl_xor(acc[j], 16, 64);
        acc[j] += __shfl_xor(acc[j], 32, 64);
    }

    if (eslot == 0 && chunk < 12) {
        bf16x8 hs = *((const bf16x8*)(H + (size_t)node * 128 + chunk * 8));
#pragma unroll
        for (int j = 0; j < 8; j++) {
            int f = chunk * 8 + j;
            float v = acc[j] + di * di * ar1_b2f((unsigned short)hs[j]) + bias[f];
            v = v * 0.9999950000374997f * gamma[f] + beta[f];   // 1/sqrt(1+1e-5)
            Out[(size_t)node * 128 + f] = ar1_f2b(fmaxf(v, 0.f));
        }
    }
}

// x -> bf16 row-major (also carries the harness kernel name)
__global__ void Arthur1_16458314678864_kernel(const void* src,
                                              unsigned short* dst, int n,
                                              const int* flagF) {
    int i = blockIdx.x * 256 + threadIdx.x;
    if (i < n) {
        if (flagF[0]) dst[i] = ar1_f2b(((const float*)src)[i]);
        else          dst[i] = ((const unsigned short*)src)[i];
    }
}

extern "C" void kernel_launch(void* const* d_in, const int* in_sizes, int n_in,
                              void* d_out, int out_size, void* d_ws, size_t ws_size,
                              hipStream_t stream) {
    (void)in_sizes; (void)n_in; (void)out_size;

    // workspace layout
    char* p = (char*)d_ws;
    unsigned short* bufB = (unsigned short*)p; p += (size_t)GN * 256 * 2;  // 25.6 MB
    unsigned short* bufA = (unsigned short*)p; p += (size_t)GN * 128 * 2;  // 12.8 MB
    unsigned short* bufX = (unsigned short*)p; p += (size_t)GN * 64 * 2;   // 6.4 MB
    int* indeg  = (int*)p;    p += (size_t)GN * 4;
    int* offs   = (int*)p;    p += (size_t)GN * 4;
    int* cursor = (int*)p;    p += (size_t)GN * 4;
    float* dinv = (float*)p;  p += (size_t)GN * 4;
    int* csr    = (int*)p;    p += (size_t)GE * 4;
    int* blksum = (int*)p;    p += 1024;
    int* blkbase= (int*)p;    p += 1024;
    int* flagI  = (int*)p;    p += 1024;
    int* flagF  = (int*)p;    p += 1024;
    unsigned short* bpArena = (unsigned short*)p; p += 91136 * 2;  // packed W
    float* fArena = (float*)p; p += 2048 * 4;                      // small fp32
    size_t need = (size_t)(p - (char*)d_ws);
    if (ws_size < need) {
        hipMemsetAsync(d_out, 0x41, (size_t)GN * 8 * 2, stream);  // marker 12.06
        return;
    }

    // packed-weight arena offsets (shorts): w1,w2,w3,lw1,lw2,lw3,lw4
    unsigned short* bp[7];
    int bpn[7] = {6144, 9216, 9216, 24576, 32768, 8192, 1024};
    {
        unsigned short* q = bpArena;
        for (int i = 0; i < 7; i++) { bp[i] = q; q += bpn[i]; }
    }

    // small fp32 arena: b1,g1,be1,b2,g2,be2,b3,g3,be3, lb1,lb2,lb3,lb4
    float* fs[13];
    int fn[13] = {96,96,96, 96,96,96, 96,96,96, 256,128,64,8};
    int fsrc[13] = {3,4,5, 7,8,9, 11,12,13, 15,17,19,21};
    {
        float* q = fArena;
        for (int i = 0; i < 13; i++) { fs[i] = q; q += fn[i]; }
    }

    const int* ei = (const int*)d_in[1];
    const int NB = (GN + 255) / 256;
    const int EB = (GE + 255) / 256;

    ar1_detect<<<2, 256, 0, stream>>>(ei, (const unsigned short*)d_in[0], flagI, flagF);
    ar1_zero<<<NB, 256, 0, stream>>>(indeg, GN);
    ar1_count<<<EB, 256, 0, stream>>>(ei, flagI, indeg, GE);
    ar1_scan1<<<NB, 256, 0, stream>>>(indeg, offs, blksum, GN);
    ar1_scan2<<<1, 256, 0, stream>>>(blksum, blkbase, NB);
    ar1_scan3<<<NB, 256, 0, stream>>>(indeg, offs, cursor, blkbase, dinv, GN);
    ar1_fill<<<EB, 256, 0, stream>>>(ei, flagI, cursor, csr, GE);

    // conversions
    Arthur1_16458314678864_kernel<<<(GN * 64 + 255) / 256, 256, 0, stream>>>(
        d_in[0], bufX, GN * 64, flagF);
    {
        SmallCvt sc;
        for (int i = 0; i < 13; i++) { sc.src[i] = d_in[fsrc[i]]; sc.dst[i] = fs[i]; sc.n[i] = fn[i]; }
        ar1_cvt_small<<<1, 256, 0, stream>>>(sc, flagF);
    }
    {
        PackAll pa;
        int wsrc[7] = {2, 6, 10, 14, 16, 18, 20};
        int Ks[7] = {64, 96, 96, 96, 256, 128, 64};
        int Ms[7] = {96, 96, 96, 256, 128, 64, 8};
        int cum = 0;
        for (int i = 0; i < 7; i++) {
            pa.src[i] = d_in[wsrc[i]]; pa.dst[i] = bp[i];
            pa.K[i] = Ks[i]; pa.M[i] = Ms[i];
            pa.start[i] = cum;
            cum += (Ms[i] + 15) / 16 * (Ks[i] / 32);
        }
        pa.start[7] = cum;   // 178
        ar1_pack_all<<<cum, 64, 0, stream>>>(pa, flagF);
    }

    const int GB = (GN + 63) / 64;    // 64 rows per block (4 waves x 16)
    const int AB = GN / 4;            // agg3: 4 nodes per block (12500 exact)

    // GCN 1..3 (A stride / C stride 128-padded; bias/BN/ReLU fused in agg)
    ar1_mfma<6><<<GB, 256, 0, stream>>>(bufX, bp[0], (const float*)0, bufB, 64, 64, 128, 96, 0, (const int*)0);
    ar1_agg3<<<AB, 256, 0, stream>>>(bufB, offs, indeg, csr, dinv, fs[0], fs[1], fs[2], bufA);
    ar1_mfma<6><<<GB, 256, 0, stream>>>(bufA, bp[1], (const float*)0, bufB, 96, 128, 128, 96, 0, (const int*)0);
    ar1_agg3<<<AB, 256, 0, stream>>>(bufB, offs, indeg, csr, dinv, fs[3], fs[4], fs[5], bufA);
    ar1_mfma<6><<<GB, 256, 0, stream>>>(bufA, bp[2], (const float*)0, bufB, 96, 128, 128, 96, 0, (const int*)0);
    ar1_agg3<<<AB, 256, 0, stream>>>(bufB, offs, indeg, csr, dinv, fs[6], fs[7], fs[8], bufA);

    // MLP: 96->256->128->64->8 (last layer writes d_out, fp32/bf16 per flagF)
    ar1_mfma<16><<<GB, 256, 0, stream>>>(bufA, bp[3], fs[9],  bufB, 96, 128, 256, 256, 1, (const int*)0);
    ar1_mfma<8><<<GB, 256, 0, stream>>>(bufB, bp[4], fs[10], bufA, 256, 256, 128, 128, 1, (const int*)0);
    ar1_mfma<4><<<GB, 256, 0, stream>>>(bufA, bp[5], fs[11], bufB, 128, 128, 64, 64, 1, (const int*)0);
    ar1_mfma<1><<<GB, 256, 0, stream>>>(bufB, bp[6], fs[12], d_out, 64, 64, 8, 8, 0, flagF);
}

// Round 14
// 379.116 us; speedup vs baseline: 1.6211x; 1.1651x over previous
//
#include <hip/hip_runtime.h>

// GCN(3 layers) + MLP(4 layers), N=50000, E=800000, out = N x 8 bf16.
// NOTE: do NOT include <hip/hip_bf16.h> — breaks this harness's build
// (rounds 1-4 fell back to a stub; round 5 proved it). Manual bf16 ushort ops.
// Dtype runtime-detection: flagI (edge_index int64 vs int32), flagF (floats
// fp32 vs packed bf16).
//
// R14: (a) CSR build v3 — LDS-staged two-phase partition sort. R13's fill
// was at the random-scatter wall (52.7 MB line-amplified writes @1.1 TB/s);
// R12's global-cursor binning serialized (512 atomics/cursor). Now: block
// bins 2048 edges via LDS counters (atomics distributed), reserves ranges
// with 98x391=38k global atomics, writes packed words into 98 L2-resident
// slabs (3.6 MB compact); pass 2 builds contiguous CSR + indeg/offs/dinv
// per partition. Replaces count+scan1/2/3+fill.
// (b) agg4: 4x edge unroll (4 independent gather chains; mean degree 16).

#define GN 50000
#define GE 800000
#define NPART 98        // partitions of 512 dst nodes
#define PSLOT 9216      // slab capacity per partition (mean 8163, +11 sigma)
#define CHK 2048        // edges per block in pass 1

typedef __attribute__((ext_vector_type(8))) short bf16x8;
typedef __attribute__((ext_vector_type(4))) float floatx4;

__device__ __forceinline__ float ar1_b2f(unsigned short h) {
    return __uint_as_float(((unsigned)h) << 16);
}
__device__ __forceinline__ unsigned short ar1_f2b(float f) {
    unsigned u = __float_as_uint(f);
    u = u + 0x7FFFu + ((u >> 16) & 1u);   // round-to-nearest-even
    return (unsigned short)(u >> 16);
}

// block 0: flagI (edge_index int64 <=> odd words ~all zero) + zero gcur
// block 1: flagF (floats fp32 vs packed bf16; see R6 notes)
__global__ void ar1_detect(const int* ei, const unsigned short* xw,
                           int* flagI, int* flagF, int* gcur) {
    __shared__ int cnt;
    if (threadIdx.x == 0) cnt = 0;
    __syncthreads();
    if (blockIdx.x == 0) {
        if ((int)threadIdx.x < NPART) gcur[threadIdx.x] = 0;
        if (ei[2 * threadIdx.x + 1] != 0) atomicAdd(&cnt, 1);
        __syncthreads();
        if (threadIdx.x == 0) flagI[0] = (cnt < 8) ? 1 : 0;
    } else {
        unsigned short w = xw[2 * threadIdx.x];
        int ex = (w >> 7) & 0xFF;
        if (w == 0 || (ex >= 90 && ex <= 150)) atomicAdd(&cnt, 1);
        __syncthreads();
        if (threadIdx.x == 0) flagF[0] = (cnt > 200) ? 0 : 1;
    }
}

// pass 1: partition edges into 98 slabs; packed word = s | (d&511)<<17
__global__ __launch_bounds__(256)
void ar1_part(const int* __restrict__ ei, const int* __restrict__ flagI,
              int* __restrict__ gcur, unsigned int* __restrict__ pairs, int E) {
    __shared__ int cnt[NPART], base[NPART], cur[NPART];
    int tid = (int)threadIdx.x;
    for (int i = tid; i < NPART; i += 256) { cnt[i] = 0; cur[i] = 0; }
    __syncthreads();
    int is64 = flagI[0];
    int e0 = (int)blockIdx.x * CHK;
    unsigned pk[8]; int q[8];
#pragma unroll
    for (int k = 0; k < 8; k++) {
        int e = e0 + k * 256 + tid;
        q[k] = -1; pk[k] = 0;
        if (e < E) {
            int s = is64 ? ei[2 * e] : ei[e];
            int d = is64 ? ei[2 * (E + e)] : ei[E + e];
            if ((unsigned)s < (unsigned)GN && (unsigned)d < (unsigned)GN) {
                int qq = d >> 9;
                q[k] = qq;
                pk[k] = (unsigned)s | ((unsigned)(d & 511) << 17);
                atomicAdd(&cnt[qq], 1);
            }
        }
    }
    __syncthreads();
    for (int i = tid; i < NPART; i += 256)
        base[i] = (cnt[i] > 0) ? atomicAdd(&gcur[i], cnt[i]) : 0;
    __syncthreads();
#pragma unroll
    for (int k = 0; k < 8; k++) {
        if (q[k] >= 0) {
            int r = base[q[k]] + atomicAdd(&cur[q[k]], 1);
            if (r < PSLOT) pairs[(size_t)q[k] * PSLOT + r] = pk[k];
        }
    }
}

// exclusive scan of partition sizes -> global CSR base per partition
__global__ void ar1_pscan(const int* gcur, int* pbase) {
    __shared__ int sm[128];
    int tid = (int)threadIdx.x;   // 128
    int v = (tid < NPART) ? gcur[tid] : 0;
    sm[tid] = v;
    __syncthreads();
    for (int off = 1; off < 128; off <<= 1) {
        int t = (tid >= off) ? sm[tid - off] : 0;
        __syncthreads();
        sm[tid] += t;
        __syncthreads();
    }
    if (tid < NPART) pbase[tid] = sm[tid] - v;
}

// pass 2: per-partition -> contiguous CSR slice + indeg/offs/dinv
__global__ __launch_bounds__(256)
void ar1_csr(const unsigned int* __restrict__ pairs, const int* __restrict__ gcur,
             const int* __restrict__ pbase, int* __restrict__ csr,
             int* __restrict__ indeg, int* __restrict__ offs,
             float* __restrict__ dinv) {
    __shared__ int ncnt[512], pre[512], cur[512], psum[16];
    int p = (int)blockIdx.x, tid = (int)threadIdx.x;
    int cntE = gcur[p];
    if (cntE > PSLOT) cntE = PSLOT;
    int gbase = pbase[p];
    for (int i = tid; i < 512; i += 256) ncnt[i] = 0;
    __syncthreads();
    const unsigned int* pp = pairs + (size_t)p * PSLOT;
    for (int i = tid; i < cntE; i += 256) atomicAdd(&ncnt[pp[i] >> 17], 1);
    __syncthreads();
    // two-level exclusive prefix over 512
    if (tid < 16) {
        int s = 0;
        for (int j = tid * 32; j < tid * 32 + 32; j++) { pre[j] = s; s += ncnt[j]; }
        psum[tid] = s;
    }
    __syncthreads();
    if (tid == 0) {
        int s = 0;
        for (int j = 0; j < 16; j++) { int t = psum[j]; psum[j] = s; s += t; }
    }
    __syncthreads();
    if (tid < 16)
        for (int j = tid * 32; j < tid * 32 + 32; j++) pre[j] += psum[tid];
    __syncthreads();
    for (int j = tid; j < 512; j += 256) {
        cur[j] = pre[j];
        int node = p * 512 + j;
        if (node < GN) {
            indeg[node] = ncnt[j];
            offs[node] = gbase + pre[j];
            dinv[node] = rsqrtf((float)(ncnt[j] + 1));   // +1: self loop
        }
    }
    __syncthreads();
    for (int i = tid; i < cntE; i += 256) {
        unsigned v = pp[i];
        int r = atomicAdd(&cur[v >> 17], 1);
        csr[gbase + r] = (int)(v & 0x1FFFFu);
    }
}

// fused small-vector -> fp32 conversion (biases, gamma, beta)
struct SmallCvt {
    const void* src[13];
    float* dst[13];
    int n[13];
};
__global__ void ar1_cvt_small(SmallCvt sc, const int* flagF) {
    int f = flagF[0];
    for (int s = 0; s < 13; s++) {
        for (int i = threadIdx.x; i < sc.n[s]; i += 256) {
            float v = f ? ((const float*)sc.src[s])[i]
                        : ar1_b2f(((const unsigned short*)sc.src[s])[i]);
            sc.dst[s][i] = v;
        }
    }
}

// fused pack of all 7 weights into MFMA B-fragment order:
// Bp[(frag*64+lane)*8+j] = bf16(W[(c*32+(lane>>4)*8+j)*M + t*16+(lane&15)]),
// frag = t*(K/32)+c; n >= M reads as 0 (lw4 M=8 padding).
struct PackAll {
    const void* src[7];
    unsigned short* dst[7];
    int K[7], M[7], start[8];
};
__global__ void ar1_pack_all(PackAll pa, const int* flagF) {
    int b = (int)blockIdx.x;
    int w = 0;
    while (w < 6 && b >= pa.start[w + 1]) w++;
    int frag = b - pa.start[w];
    int K = pa.K[w], M = pa.M[w];
    int lane = (int)threadIdx.x;
    int nch = K >> 5;
    int t = frag / nch, c = frag - t * nch;
    int n = t * 16 + (lane & 15);
    int k0 = c * 32 + (lane >> 4) * 8;
    int f = flagF[0];
    unsigned short* o = pa.dst[w] + ((size_t)frag * 64 + lane) * 8;
    for (int j = 0; j < 8; j++) {
        unsigned short v = 0;
        if (n < M) {
            int idx = (k0 + j) * M + n;
            v = f ? ar1_f2b(((const float*)pa.src[w])[idx])
                  : ((const unsigned short*)pa.src[w])[idx];
        }
        o[j] = v;
    }
}

// ---------------- MFMA GEMM: C[GN,Mout] = A[GN,K] @ W[K,M] (+bias)(+relu) ---
// A bf16 rows of Astride; C rows of Cstride (bf16, or fp32 if f32out&&*f32out).
// Bp packed fragments; fp32 accum; NT*16 = padded M; K mult of 32.
template <int NT>
__global__ __launch_bounds__(256, 2)
void ar1_mfma(const unsigned short* __restrict__ A,
              const unsigned short* __restrict__ Bp,
              const float* __restrict__ bias,
              void* __restrict__ C, int K, int Astride, int Cstride,
              int Mout, int relu, const int* f32out) {
    int tid = (int)threadIdx.x;
    int wv = tid >> 6, lane = tid & 63;
    int mb = ((int)blockIdx.x * 4 + wv) * 16;
    int m = lane & 15, quad = lane >> 4;
    int arow = mb + m;
    if (arow >= GN) arow = GN - 1;          // clamp; rows >= GN never stored
    const unsigned short* Aptr = A + (size_t)arow * Astride + quad * 8;
    int nch = K >> 5;

    floatx4 acc[NT];
#pragma unroll
    for (int t = 0; t < NT; t++) acc[t] = (floatx4){0.f, 0.f, 0.f, 0.f};

    for (int c = 0; c < nch; c++) {
        bf16x8 a = *((const bf16x8*)(Aptr + c * 32));
#pragma unroll
        for (int t = 0; t < NT; t++) {
            bf16x8 b = *((const bf16x8*)(Bp + ((size_t)(t * nch + c) * 64 + lane) * 8));
            acc[t] = __builtin_amdgcn_mfma_f32_16x16x32_bf16(a, b, acc[t], 0, 0, 0);
        }
    }

    int wf32 = (f32out != (const int*)0) ? f32out[0] : 0;
#pragma unroll
    for (int t = 0; t < NT; t++) {
#pragma unroll
        for (int r = 0; r < 4; r++) {
            int row = mb + quad * 4 + r;
            int col = t * 16 + m;
            if (row < GN && col < Mout) {
                float v = acc[t][r];
                if (bias) v += bias[col];
                if (relu) v = fmaxf(v, 0.f);
                if (wf32) ((float*)C)[(size_t)row * Cstride + col] = v;
                else ((unsigned short*)C)[(size_t)row * Cstride + col] = ar1_f2b(v);
            }
        }
    }
}

// ---------------- GCN aggregate v4 ------------------------------------------
// H rows padded to 128 bf16 (256 B). Wave per node: lane = eslot(2b) x chunk
// (4b). 4x edge unroll: four independent gather chains per lane (mean deg 16
// -> typically one iteration). fp32 acc x8; shfl_xor reduce; fused epilogue.
__global__ __launch_bounds__(256, 8)
void ar1_agg4(const unsigned short* __restrict__ H, const int* __restrict__ offs,
              const int* __restrict__ indeg, const int* __restrict__ csr,
              const float* __restrict__ dinv,
              const float* __restrict__ bias, const float* __restrict__ gamma,
              const float* __restrict__ beta, unsigned short* __restrict__ Out) {
    int wv = (int)threadIdx.x >> 6, lane = (int)threadIdx.x & 63;
    int node = (int)blockIdx.x * 4 + wv;
    if (node >= GN) return;
    int chunk = lane & 15;     // feature chunk: feats chunk*8 .. +8
    int eslot = lane >> 4;     // 0..3
    float di = dinv[node];
    int off = offs[node], cnt = indeg[node];

    float acc[8];
#pragma unroll
    for (int j = 0; j < 8; j++) acc[j] = 0.f;

    for (int base = 0; base < cnt; base += 16) {
        int ss[4]; float ww[4]; bf16x8 hh[4];
#pragma unroll
        for (int k = 0; k < 4; k++) {
            int e = base + k * 4 + eslot;
            int s = node; float w = 0.f;
            if (e < cnt) {
                s = csr[off + e];
                if ((unsigned)s >= (unsigned)GN) s = node;
                w = dinv[s] * di;
            }
            ss[k] = s; ww[k] = w;
        }
#pragma unroll
        for (int k = 0; k < 4; k++)
            hh[k] = *((const bf16x8*)(H + (size_t)ss[k] * 128 + chunk * 8));
#pragma unroll
        for (int k = 0; k < 4; k++)
#pragma unroll
            for (int j = 0; j < 8; j++)
                acc[j] += ww[k] * ar1_b2f((unsigned short)hh[k][j]);
    }

    // reduce partial sums across the 4 edge-slot groups
#pragma unroll
    for (int j = 0; j < 8; j++) {
        acc[j] += __shfl_xor(acc[j], 16, 64);
        acc[j] += __shfl_xor(acc[j], 32, 64);
    }

    if (eslot == 0 && chunk < 12) {
        bf16x8 hs = *((const bf16x8*)(H + (size_t)node * 128 + chunk * 8));
#pragma unroll
        for (int j = 0; j < 8; j++) {
            int f = chunk * 8 + j;
            float v = acc[j] + di * di * ar1_b2f((unsigned short)hs[j]) + bias[f];
            v = v * 0.9999950000374997f * gamma[f] + beta[f];   // 1/sqrt(1+1e-5)
            Out[(size_t)node * 128 + f] = ar1_f2b(fmaxf(v, 0.f));
        }
    }
}

// x -> bf16 row-major (also carries the harness kernel name)
__global__ void Arthur1_16458314678864_kernel(const void* src,
                                              unsigned short* dst, int n,
                                              const int* flagF) {
    int i = blockIdx.x * 256 + threadIdx.x;
    if (i < n) {
        if (flagF[0]) dst[i] = ar1_f2b(((const float*)src)[i]);
        else          dst[i] = ((const unsigned short*)src)[i];
    }
}

extern "C" void kernel_launch(void* const* d_in, const int* in_sizes, int n_in,
                              void* d_out, int out_size, void* d_ws, size_t ws_size,
                              hipStream_t stream) {
    (void)in_sizes; (void)n_in; (void)out_size;

    // workspace layout
    char* p = (char*)d_ws;
    unsigned short* bufB = (unsigned short*)p; p += (size_t)GN * 256 * 2;  // 25.6 MB
    unsigned short* bufA = (unsigned short*)p; p += (size_t)GN * 128 * 2;  // 12.8 MB
    unsigned short* bufX = (unsigned short*)p; p += (size_t)GN * 64 * 2;   // 6.4 MB
    unsigned int* pairs = (unsigned int*)p; p += (size_t)NPART * PSLOT * 4; // 3.6 MB
    int* indeg  = (int*)p;    p += (size_t)GN * 4;
    int* offs   = (int*)p;    p += (size_t)GN * 4;
    float* dinv = (float*)p;  p += (size_t)GN * 4;
    int* csr    = (int*)p;    p += (size_t)GE * 4;
    int* gcur   = (int*)p;    p += 1024;
    int* pbase  = (int*)p;    p += 1024;
    int* flagI  = (int*)p;    p += 1024;
    int* flagF  = (int*)p;    p += 1024;
    unsigned short* bpArena = (unsigned short*)p; p += 91136 * 2;  // packed W
    float* fArena = (float*)p; p += 2048 * 4;                      // small fp32
    size_t need = (size_t)(p - (char*)d_ws);
    if (ws_size < need) {
        hipMemsetAsync(d_out, 0x41, (size_t)GN * 8 * 2, stream);  // marker 12.06
        return;
    }

    // packed-weight arena offsets (shorts): w1,w2,w3,lw1,lw2,lw3,lw4
    unsigned short* bp[7];
    int bpn[7] = {6144, 9216, 9216, 24576, 32768, 8192, 1024};
    {
        unsigned short* q = bpArena;
        for (int i = 0; i < 7; i++) { bp[i] = q; q += bpn[i]; }
    }

    // small fp32 arena: b1,g1,be1,b2,g2,be2,b3,g3,be3, lb1,lb2,lb3,lb4
    float* fs[13];
    int fn[13] = {96,96,96, 96,96,96, 96,96,96, 256,128,64,8};
    int fsrc[13] = {3,4,5, 7,8,9, 11,12,13, 15,17,19,21};
    {
        float* q = fArena;
        for (int i = 0; i < 13; i++) { fs[i] = q; q += fn[i]; }
    }

    const int* ei = (const int*)d_in[1];

    // graph build v3
    ar1_detect<<<2, 256, 0, stream>>>(ei, (const unsigned short*)d_in[0], flagI, flagF, gcur);
    ar1_part<<<(GE + CHK - 1) / CHK, 256, 0, stream>>>(ei, flagI, gcur, pairs, GE);
    ar1_pscan<<<1, 128, 0, stream>>>(gcur, pbase);
    ar1_csr<<<NPART, 256, 0, stream>>>(pairs, gcur, pbase, csr, indeg, offs, dinv);

    // conversions
    Arthur1_16458314678864_kernel<<<(GN * 64 + 255) / 256, 256, 0, stream>>>(
        d_in[0], bufX, GN * 64, flagF);
    {
        SmallCvt sc;
        for (int i = 0; i < 13; i++) { sc.src[i] = d_in[fsrc[i]]; sc.dst[i] = fs[i]; sc.n[i] = fn[i]; }
        ar1_cvt_small<<<1, 256, 0, stream>>>(sc, flagF);
    }
    {
        PackAll pa;
        int wsrc[7] = {2, 6, 10, 14, 16, 18, 20};
        int Ks[7] = {64, 96, 96, 96, 256, 128, 64};
        int Ms[7] = {96, 96, 96, 256, 128, 64, 8};
        int cum = 0;
        for (int i = 0; i < 7; i++) {
            pa.src[i] = d_in[wsrc[i]]; pa.dst[i] = bp[i];
            pa.K[i] = Ks[i]; pa.M[i] = Ms[i];
            pa.start[i] = cum;
            cum += (Ms[i] + 15) / 16 * (Ks[i] / 32);
        }
        pa.start[7] = cum;   // 178
        ar1_pack_all<<<cum, 64, 0, stream>>>(pa, flagF);
    }

    const int GB = (GN + 63) / 64;    // 64 rows per block (4 waves x 16)
    const int AB = GN / 4;            // agg4: 4 nodes per block (12500 exact)

    // GCN 1..3 (A stride / C stride 128-padded; bias/BN/ReLU fused in agg)
    ar1_mfma<6><<<GB, 256, 0, stream>>>(bufX, bp[0], (const float*)0, bufB, 64, 64, 128, 96, 0, (const int*)0);
    ar1_agg4<<<AB, 256, 0, stream>>>(bufB, offs, indeg, csr, dinv, fs[0], fs[1], fs[2], bufA);
    ar1_mfma<6><<<GB, 256, 0, stream>>>(bufA, bp[1], (const float*)0, bufB, 96, 128, 128, 96, 0, (const int*)0);
    ar1_agg4<<<AB, 256, 0, stream>>>(bufB, offs, indeg, csr, dinv, fs[3], fs[4], fs[5], bufA);
    ar1_mfma<6><<<GB, 256, 0, stream>>>(bufA, bp[2], (const float*)0, bufB, 96, 128, 128, 96, 0, (const int*)0);
    ar1_agg4<<<AB, 256, 0, stream>>>(bufB, offs, indeg, csr, dinv, fs[6], fs[7], fs[8], bufA);

    // MLP: 96->256->128->64->8 (last layer writes d_out, fp32/bf16 per flagF)
    ar1_mfma<16><<<GB, 256, 0, stream>>>(bufA, bp[3], fs[9],  bufB, 96, 128, 256, 256, 1, (const int*)0);
    ar1_mfma<8><<<GB, 256, 0, stream>>>(bufB, bp[4], fs[10], bufA, 256, 256, 128, 128, 1, (const int*)0);
    ar1_mfma<4><<<GB, 256, 0, stream>>>(bufA, bp[5], fs[11], bufB, 128, 128, 64, 64, 1, (const int*)0);
    ar1_mfma<1><<<GB, 256, 0, stream>>>(bufB, bp[6], fs[12], d_out, 64, 64, 8, 8, 0, flagF);
}

// Round 15
// 367.141 us; speedup vs baseline: 1.6739x; 1.0326x over previous
//
#include <hip/hip_runtime.h>

// GCN(3 layers) + MLP(4 layers), N=50000, E=800000, out = N x 8 bf16.
// NOTE: do NOT include <hip/hip_bf16.h> — breaks this harness's build
// (rounds 1-4 fell back to a stub; round 5 proved it). Manual bf16 ushort ops.
// Dtype runtime-detection: flagI (edge_index int64 vs int32), flagF (floats
// fp32 vs packed bf16).
//
// R15: GCN layers reordered agg-then-gemm via S(xW)=(Sx)W linearity.
// Layer-1 aggregate now gathers 64-dim x rows (128 B = 1 cache line/edge,
// and x=6.4MB mostly fits per-XCD L2) vs 96-dim padded 256 B rows (R14 agg:
// 45us, FETCH 83.8MB = ~8 XCD x full H). bias+BN folded into mfma epilogue
// as per-col affine (scale=C*gamma, shift=b*C*gamma+beta — exact).
// Graph build: R14 partition sort (kept). agg has no epilogue now.

#define GN 50000
#define GE 800000
#define NPART 98        // partitions of 512 dst nodes
#define PSLOT 9216      // slab capacity per partition (mean 8163, +11 sigma)
#define CHK 2048        // edges per block in pass 1

typedef __attribute__((ext_vector_type(8))) short bf16x8;
typedef __attribute__((ext_vector_type(4))) float floatx4;

__device__ __forceinline__ float ar1_b2f(unsigned short h) {
    return __uint_as_float(((unsigned)h) << 16);
}
__device__ __forceinline__ unsigned short ar1_f2b(float f) {
    unsigned u = __float_as_uint(f);
    u = u + 0x7FFFu + ((u >> 16) & 1u);   // round-to-nearest-even
    return (unsigned short)(u >> 16);
}

// block 0: flagI (edge_index int64 <=> odd words ~all zero) + zero gcur
// block 1: flagF (floats fp32 vs packed bf16; see R6 notes)
__global__ void ar1_detect(const int* ei, const unsigned short* xw,
                           int* flagI, int* flagF, int* gcur) {
    __shared__ int cnt;
    if (threadIdx.x == 0) cnt = 0;
    __syncthreads();
    if (blockIdx.x == 0) {
        if ((int)threadIdx.x < NPART) gcur[threadIdx.x] = 0;
        if (ei[2 * threadIdx.x + 1] != 0) atomicAdd(&cnt, 1);
        __syncthreads();
        if (threadIdx.x == 0) flagI[0] = (cnt < 8) ? 1 : 0;
    } else {
        unsigned short w = xw[2 * threadIdx.x];
        int ex = (w >> 7) & 0xFF;
        if (w == 0 || (ex >= 90 && ex <= 150)) atomicAdd(&cnt, 1);
        __syncthreads();
        if (threadIdx.x == 0) flagF[0] = (cnt > 200) ? 0 : 1;
    }
}

// pass 1: partition edges into 98 slabs; packed word = s | (d&511)<<17
__global__ __launch_bounds__(256)
void ar1_part(const int* __restrict__ ei, const int* __restrict__ flagI,
              int* __restrict__ gcur, unsigned int* __restrict__ pairs, int E) {
    __shared__ int cnt[NPART], base[NPART], cur[NPART];
    int tid = (int)threadIdx.x;
    for (int i = tid; i < NPART; i += 256) { cnt[i] = 0; cur[i] = 0; }
    __syncthreads();
    int is64 = flagI[0];
    int e0 = (int)blockIdx.x * CHK;
    unsigned pk[8]; int q[8];
#pragma unroll
    for (int k = 0; k < 8; k++) {
        int e = e0 + k * 256 + tid;
        q[k] = -1; pk[k] = 0;
        if (e < E) {
            int s = is64 ? ei[2 * e] : ei[e];
            int d = is64 ? ei[2 * (E + e)] : ei[E + e];
            if ((unsigned)s < (unsigned)GN && (unsigned)d < (unsigned)GN) {
                int qq = d >> 9;
                q[k] = qq;
                pk[k] = (unsigned)s | ((unsigned)(d & 511) << 17);
                atomicAdd(&cnt[qq], 1);
            }
        }
    }
    __syncthreads();
    for (int i = tid; i < NPART; i += 256)
        base[i] = (cnt[i] > 0) ? atomicAdd(&gcur[i], cnt[i]) : 0;
    __syncthreads();
#pragma unroll
    for (int k = 0; k < 8; k++) {
        if (q[k] >= 0) {
            int r = base[q[k]] + atomicAdd(&cur[q[k]], 1);
            if (r < PSLOT) pairs[(size_t)q[k] * PSLOT + r] = pk[k];
        }
    }
}

// exclusive scan of partition sizes -> global CSR base per partition
__global__ void ar1_pscan(const int* gcur, int* pbase) {
    __shared__ int sm[128];
    int tid = (int)threadIdx.x;   // 128
    int v = (tid < NPART) ? gcur[tid] : 0;
    sm[tid] = v;
    __syncthreads();
    for (int off = 1; off < 128; off <<= 1) {
        int t = (tid >= off) ? sm[tid - off] : 0;
        __syncthreads();
        sm[tid] += t;
        __syncthreads();
    }
    if (tid < NPART) pbase[tid] = sm[tid] - v;
}

// pass 2: per-partition -> contiguous CSR slice + indeg/offs/dinv
__global__ __launch_bounds__(256)
void ar1_csr(const unsigned int* __restrict__ pairs, const int* __restrict__ gcur,
             const int* __restrict__ pbase, int* __restrict__ csr,
             int* __restrict__ indeg, int* __restrict__ offs,
             float* __restrict__ dinv) {
    __shared__ int ncnt[512], pre[512], cur[512], psum[16];
    int p = (int)blockIdx.x, tid = (int)threadIdx.x;
    int cntE = gcur[p];
    if (cntE > PSLOT) cntE = PSLOT;
    int gbase = pbase[p];
    for (int i = tid; i < 512; i += 256) ncnt[i] = 0;
    __syncthreads();
    const unsigned int* pp = pairs + (size_t)p * PSLOT;
    for (int i = tid; i < cntE; i += 256) atomicAdd(&ncnt[pp[i] >> 17], 1);
    __syncthreads();
    // two-level exclusive prefix over 512
    if (tid < 16) {
        int s = 0;
        for (int j = tid * 32; j < tid * 32 + 32; j++) { pre[j] = s; s += ncnt[j]; }
        psum[tid] = s;
    }
    __syncthreads();
    if (tid == 0) {
        int s = 0;
        for (int j = 0; j < 16; j++) { int t = psum[j]; psum[j] = s; s += t; }
    }
    __syncthreads();
    if (tid < 16)
        for (int j = tid * 32; j < tid * 32 + 32; j++) pre[j] += psum[tid];
    __syncthreads();
    for (int j = tid; j < 512; j += 256) {
        cur[j] = pre[j];
        int node = p * 512 + j;
        if (node < GN) {
            indeg[node] = ncnt[j];
            offs[node] = gbase + pre[j];
            dinv[node] = rsqrtf((float)(ncnt[j] + 1));   // +1: self loop
        }
    }
    __syncthreads();
    for (int i = tid; i < cntE; i += 256) {
        unsigned v = pp[i];
        int r = atomicAdd(&cur[v >> 17], 1);
        csr[gbase + r] = (int)(v & 0x1FFFFu);
    }
}

// MLP biases -> fp32, plus GCN bias/BN fold: scale=C*g, shift=b*C*g+be
struct SmallCvt {
    const void* src[4];   // lb1, lb2, lb3, lb4
    float* dst[4];
    int n[4];
    const void* gb[9];    // b1,g1,be1, b2,g2,be2, b3,g3,be3
    float* ss[6];         // scale1,shift1, scale2,shift2, scale3,shift3
};
__global__ void ar1_cvt_small(SmallCvt sc, const int* flagF) {
    int f = flagF[0];
    const float C = 0.9999950000374997f;   // 1/sqrt(1+1e-5)
    for (int s = 0; s < 4; s++) {
        for (int i = threadIdx.x; i < sc.n[s]; i += 256) {
            float v = f ? ((const float*)sc.src[s])[i]
                        : ar1_b2f(((const unsigned short*)sc.src[s])[i]);
            sc.dst[s][i] = v;
        }
    }
    for (int k = 0; k < 3; k++) {
        for (int i = threadIdx.x; i < 96; i += 256) {
            float b, g, be;
            if (f) {
                b  = ((const float*)sc.gb[3 * k + 0])[i];
                g  = ((const float*)sc.gb[3 * k + 1])[i];
                be = ((const float*)sc.gb[3 * k + 2])[i];
            } else {
                b  = ar1_b2f(((const unsigned short*)sc.gb[3 * k + 0])[i]);
                g  = ar1_b2f(((const unsigned short*)sc.gb[3 * k + 1])[i]);
                be = ar1_b2f(((const unsigned short*)sc.gb[3 * k + 2])[i]);
            }
            sc.ss[2 * k + 0][i] = C * g;
            sc.ss[2 * k + 1][i] = b * C * g + be;
        }
    }
}

// fused pack of all 7 weights into MFMA B-fragment order (see R10 notes)
struct PackAll {
    const void* src[7];
    unsigned short* dst[7];
    int K[7], M[7], start[8];
};
__global__ void ar1_pack_all(PackAll pa, const int* flagF) {
    int b = (int)blockIdx.x;
    int w = 0;
    while (w < 6 && b >= pa.start[w + 1]) w++;
    int frag = b - pa.start[w];
    int K = pa.K[w], M = pa.M[w];
    int lane = (int)threadIdx.x;
    int nch = K >> 5;
    int t = frag / nch, c = frag - t * nch;
    int n = t * 16 + (lane & 15);
    int k0 = c * 32 + (lane >> 4) * 8;
    int f = flagF[0];
    unsigned short* o = pa.dst[w] + ((size_t)frag * 64 + lane) * 8;
    for (int j = 0; j < 8; j++) {
        unsigned short v = 0;
        if (n < M) {
            int idx = (k0 + j) * M + n;
            v = f ? ar1_f2b(((const float*)pa.src[w])[idx])
                  : ((const unsigned short*)pa.src[w])[idx];
        }
        o[j] = v;
    }
}

// ---------------- MFMA GEMM: C[GN,Mout] = A[GN,K] @ W[K,M] + epilogue -------
// Epilogue: if scale: v = v*scale[col]+shift[col]; elif bias: v += bias[col];
// then optional relu. A bf16 rows of Astride; C bf16 (or fp32 if *f32out).
template <int NT>
__global__ __launch_bounds__(256, 2)
void ar1_mfma(const unsigned short* __restrict__ A,
              const unsigned short* __restrict__ Bp,
              const float* __restrict__ bias,
              const float* __restrict__ scale, const float* __restrict__ shift,
              void* __restrict__ C, int K, int Astride, int Cstride,
              int Mout, int relu, const int* f32out) {
    int tid = (int)threadIdx.x;
    int wv = tid >> 6, lane = tid & 63;
    int mb = ((int)blockIdx.x * 4 + wv) * 16;
    int m = lane & 15, quad = lane >> 4;
    int arow = mb + m;
    if (arow >= GN) arow = GN - 1;          // clamp; rows >= GN never stored
    const unsigned short* Aptr = A + (size_t)arow * Astride + quad * 8;
    int nch = K >> 5;

    floatx4 acc[NT];
#pragma unroll
    for (int t = 0; t < NT; t++) acc[t] = (floatx4){0.f, 0.f, 0.f, 0.f};

    for (int c = 0; c < nch; c++) {
        bf16x8 a = *((const bf16x8*)(Aptr + c * 32));
#pragma unroll
        for (int t = 0; t < NT; t++) {
            bf16x8 b = *((const bf16x8*)(Bp + ((size_t)(t * nch + c) * 64 + lane) * 8));
            acc[t] = __builtin_amdgcn_mfma_f32_16x16x32_bf16(a, b, acc[t], 0, 0, 0);
        }
    }

    int wf32 = (f32out != (const int*)0) ? f32out[0] : 0;
#pragma unroll
    for (int t = 0; t < NT; t++) {
#pragma unroll
        for (int r = 0; r < 4; r++) {
            int row = mb + quad * 4 + r;
            int col = t * 16 + m;
            if (row < GN && col < Mout) {
                float v = acc[t][r];
                if (scale) v = v * scale[col] + shift[col];
                else if (bias) v += bias[col];
                if (relu) v = fmaxf(v, 0.f);
                if (wf32) ((float*)C)[(size_t)row * Cstride + col] = v;
                else ((unsigned short*)C)[(size_t)row * Cstride + col] = ar1_f2b(v);
            }
        }
    }
}

// ---------------- aggregate, 64-dim rows (layer 1, on x) --------------------
// X rows stride 64 (128 B = 1 line). lane = eslot(3b) x chunk(3b): 8 edges
// in flight x 8 feats; 2x unroll (16 edges/iter). Pure weighted sum + self.
__global__ __launch_bounds__(256, 8)
void ar1_agg64(const unsigned short* __restrict__ X, const int* __restrict__ offs,
               const int* __restrict__ indeg, const int* __restrict__ csr,
               const float* __restrict__ dinv, unsigned short* __restrict__ Out) {
    int wv = (int)threadIdx.x >> 6, lane = (int)threadIdx.x & 63;
    int node = (int)blockIdx.x * 4 + wv;
    if (node >= GN) return;
    int chunk = lane & 7;      // feats chunk*8 .. +8
    int eslot = lane >> 3;     // 0..7
    float di = dinv[node];
    int off = offs[node], cnt = indeg[node];

    float acc[8];
#pragma unroll
    for (int j = 0; j < 8; j++) acc[j] = 0.f;

    for (int base = 0; base < cnt; base += 16) {
        int ss[2]; float ww[2];
#pragma unroll
        for (int k = 0; k < 2; k++) {
            int e = base + k * 8 + eslot;
            int s = node; float w = 0.f;
            if (e < cnt) {
                s = csr[off + e];
                if ((unsigned)s >= (unsigned)GN) s = node;
                w = dinv[s] * di;
            }
            ss[k] = s; ww[k] = w;
        }
        bf16x8 h0 = *((const bf16x8*)(X + (size_t)ss[0] * 64 + chunk * 8));
        bf16x8 h1 = *((const bf16x8*)(X + (size_t)ss[1] * 64 + chunk * 8));
#pragma unroll
        for (int j = 0; j < 8; j++)
            acc[j] += ww[0] * ar1_b2f((unsigned short)h0[j])
                    + ww[1] * ar1_b2f((unsigned short)h1[j]);
    }

#pragma unroll
    for (int j = 0; j < 8; j++) {
        acc[j] += __shfl_xor(acc[j], 8, 64);
        acc[j] += __shfl_xor(acc[j], 16, 64);
        acc[j] += __shfl_xor(acc[j], 32, 64);
    }

    if (eslot == 0) {
        bf16x8 hs = *((const bf16x8*)(X + (size_t)node * 64 + chunk * 8));
#pragma unroll
        for (int j = 0; j < 8; j++) {
            float v = acc[j] + di * di * ar1_b2f((unsigned short)hs[j]);
            Out[(size_t)node * 64 + chunk * 8 + j] = ar1_f2b(v);
        }
    }
}

// ---------------- aggregate, 96-dim rows padded 128 (layers 2,3) ------------
// lane = eslot(2b) x chunk(4b); 4x unroll. Pure weighted sum + self loop.
__global__ __launch_bounds__(256, 8)
void ar1_agg96(const unsigned short* __restrict__ H, const int* __restrict__ offs,
               const int* __restrict__ indeg, const int* __restrict__ csr,
               const float* __restrict__ dinv, unsigned short* __restrict__ Out) {
    int wv = (int)threadIdx.x >> 6, lane = (int)threadIdx.x & 63;
    int node = (int)blockIdx.x * 4 + wv;
    if (node >= GN) return;
    int chunk = lane & 15;
    int eslot = lane >> 4;
    float di = dinv[node];
    int off = offs[node], cnt = indeg[node];

    float acc[8];
#pragma unroll
    for (int j = 0; j < 8; j++) acc[j] = 0.f;

    for (int base = 0; base < cnt; base += 16) {
        int ss[4]; float ww[4]; bf16x8 hh[4];
#pragma unroll
        for (int k = 0; k < 4; k++) {
            int e = base + k * 4 + eslot;
            int s = node; float w = 0.f;
            if (e < cnt) {
                s = csr[off + e];
                if ((unsigned)s >= (unsigned)GN) s = node;
                w = dinv[s] * di;
            }
            ss[k] = s; ww[k] = w;
        }
#pragma unroll
        for (int k = 0; k < 4; k++)
            hh[k] = *((const bf16x8*)(H + (size_t)ss[k] * 128 + chunk * 8));
#pragma unroll
        for (int k = 0; k < 4; k++)
#pragma unroll
            for (int j = 0; j < 8; j++)
                acc[j] += ww[k] * ar1_b2f((unsigned short)hh[k][j]);
    }

#pragma unroll
    for (int j = 0; j < 8; j++) {
        acc[j] += __shfl_xor(acc[j], 16, 64);
        acc[j] += __shfl_xor(acc[j], 32, 64);
    }

    if (eslot == 0 && chunk < 12) {
        bf16x8 hs = *((const bf16x8*)(H + (size_t)node * 128 + chunk * 8));
#pragma unroll
        for (int j = 0; j < 8; j++) {
            float v = acc[j] + di * di * ar1_b2f((unsigned short)hs[j]);
            Out[(size_t)node * 128 + chunk * 8 + j] = ar1_f2b(v);
        }
    }
}

// x -> bf16 row-major (also carries the harness kernel name)
__global__ void Arthur1_16458314678864_kernel(const void* src,
                                              unsigned short* dst, int n,
                                              const int* flagF) {
    int i = blockIdx.x * 256 + threadIdx.x;
    if (i < n) {
        if (flagF[0]) dst[i] = ar1_f2b(((const float*)src)[i]);
        else          dst[i] = ((const unsigned short*)src)[i];
    }
}

extern "C" void kernel_launch(void* const* d_in, const int* in_sizes, int n_in,
                              void* d_out, int out_size, void* d_ws, size_t ws_size,
                              hipStream_t stream) {
    (void)in_sizes; (void)n_in; (void)out_size;

    // workspace layout
    char* p = (char*)d_ws;
    unsigned short* bufB = (unsigned short*)p; p += (size_t)GN * 256 * 2;  // 25.6 MB
    unsigned short* bufA = (unsigned short*)p; p += (size_t)GN * 128 * 2;  // 12.8 MB
    unsigned short* bufC = (unsigned short*)p; p += (size_t)GN * 128 * 2;  // 12.8 MB
    unsigned short* bufX = (unsigned short*)p; p += (size_t)GN * 64 * 2;   // 6.4 MB
    unsigned int* pairs = (unsigned int*)p; p += (size_t)NPART * PSLOT * 4; // 3.6 MB
    int* indeg  = (int*)p;    p += (size_t)GN * 4;
    int* offs   = (int*)p;    p += (size_t)GN * 4;
    float* dinv = (float*)p;  p += (size_t)GN * 4;
    int* csr    = (int*)p;    p += (size_t)GE * 4;
    int* gcur   = (int*)p;    p += 1024;
    int* pbase  = (int*)p;    p += 1024;
    int* flagI  = (int*)p;    p += 1024;
    int* flagF  = (int*)p;    p += 1024;
    unsigned short* bpArena = (unsigned short*)p; p += 91136 * 2;  // packed W
    float* fArena = (float*)p; p += 2048 * 4;                      // small fp32
    size_t need = (size_t)(p - (char*)d_ws);
    if (ws_size < need) {
        hipMemsetAsync(d_out, 0x41, (size_t)GN * 8 * 2, stream);  // marker 12.06
        return;
    }

    // packed-weight arena offsets (shorts): w1,w2,w3,lw1,lw2,lw3,lw4
    unsigned short* bp[7];
    int bpn[7] = {6144, 9216, 9216, 24576, 32768, 8192, 1024};
    {
        unsigned short* q = bpArena;
        for (int i = 0; i < 7; i++) { bp[i] = q; q += bpn[i]; }
    }

    // small fp32 arena: lb1(256),lb2(128),lb3(64),lb4(8), 6 x 96 scale/shift
    float* lb[4]; float* ss[6];
    {
        float* q = fArena;
        int ln[4] = {256, 128, 64, 8};
        for (int i = 0; i < 4; i++) { lb[i] = q; q += ln[i]; }
        for (int i = 0; i < 6; i++) { ss[i] = q; q += 96; }
    }

    const int* ei = (const int*)d_in[1];

    // graph build (partition sort)
    ar1_detect<<<2, 256, 0, stream>>>(ei, (const unsigned short*)d_in[0], flagI, flagF, gcur);
    ar1_part<<<(GE + CHK - 1) / CHK, 256, 0, stream>>>(ei, flagI, gcur, pairs, GE);
    ar1_pscan<<<1, 128, 0, stream>>>(gcur, pbase);
    ar1_csr<<<NPART, 256, 0, stream>>>(pairs, gcur, pbase, csr, indeg, offs, dinv);

    // conversions
    Arthur1_16458314678864_kernel<<<(GN * 64 + 255) / 256, 256, 0, stream>>>(
        d_in[0], bufX, GN * 64, flagF);
    {
        SmallCvt sc;
        int lsrc[4] = {15, 17, 19, 21};
        int ln[4] = {256, 128, 64, 8};
        for (int i = 0; i < 4; i++) { sc.src[i] = d_in[lsrc[i]]; sc.dst[i] = lb[i]; sc.n[i] = ln[i]; }
        int gsrc[9] = {3, 4, 5, 7, 8, 9, 11, 12, 13};
        for (int i = 0; i < 9; i++) sc.gb[i] = d_in[gsrc[i]];
        for (int i = 0; i < 6; i++) sc.ss[i] = ss[i];
        ar1_cvt_small<<<1, 256, 0, stream>>>(sc, flagF);
    }
    {
        PackAll pa;
        int wsrc[7] = {2, 6, 10, 14, 16, 18, 20};
        int Ks[7] = {64, 96, 96, 96, 256, 128, 64};
        int Ms[7] = {96, 96, 96, 256, 128, 64, 8};
        int cum = 0;
        for (int i = 0; i < 7; i++) {
            pa.src[i] = d_in[wsrc[i]]; pa.dst[i] = bp[i];
            pa.K[i] = Ks[i]; pa.M[i] = Ms[i];
            pa.start[i] = cum;
            cum += (Ms[i] + 15) / 16 * (Ks[i] / 32);
        }
        pa.start[7] = cum;   // 178
        ar1_pack_all<<<cum, 64, 0, stream>>>(pa, flagF);
    }

    const int GB = (GN + 63) / 64;    // mfma: 64 rows per block
    const int AB = GN / 4;            // agg: 4 nodes per block (12500 exact)
    const float* nul = (const float*)0;

    // GCN 1..3: aggregate first (linearity), then GEMM with affine epilogue
    ar1_agg64<<<AB, 256, 0, stream>>>(bufX, offs, indeg, csr, dinv, bufC);
    ar1_mfma<6><<<GB, 256, 0, stream>>>(bufC, bp[0], nul, ss[0], ss[1], bufA, 64, 64, 128, 96, 1, (const int*)0);
    ar1_agg96<<<AB, 256, 0, stream>>>(bufA, offs, indeg, csr, dinv, bufC);
    ar1_mfma<6><<<GB, 256, 0, stream>>>(bufC, bp[1], nul, ss[2], ss[3], bufA, 96, 128, 128, 96, 1, (const int*)0);
    ar1_agg96<<<AB, 256, 0, stream>>>(bufA, offs, indeg, csr, dinv, bufC);
    ar1_mfma<6><<<GB, 256, 0, stream>>>(bufC, bp[2], nul, ss[4], ss[5], bufA, 96, 128, 128, 96, 1, (const int*)0);

    // MLP: 96->256->128->64->8 (last layer writes d_out, fp32/bf16 per flagF)
    ar1_mfma<16><<<GB, 256, 0, stream>>>(bufA, bp[3], lb[0], nul, nul, bufB, 96, 128, 256, 256, 1, (const int*)0);
    ar1_mfma<8><<<GB, 256, 0, stream>>>(bufB, bp[4], lb[1], nul, nul, bufA, 256, 256, 128, 128, 1, (const int*)0);
    ar1_mfma<4><<<GB, 256, 0, stream>>>(bufA, bp[5], lb[2], nul, nul, bufC, 128, 128, 64, 64, 1, (const int*)0);
    ar1_mfma<1><<<GB, 256, 0, stream>>>(bufC, bp[6], lb[3], nul, nul, d_out, 64, 64, 8, 8, 0, flagF);
}

// Round 16
// 331.485 us; speedup vs baseline: 1.8540x; 1.1076x over previous
//
#include <hip/hip_runtime.h>

// GCN(3 layers) + MLP(4 layers), N=50000, E=800000, out = N x 8 bf16.
// NOTE: do NOT include <hip/hip_bf16.h> — breaks this harness's build
// (rounds 1-4 fell back to a stub; round 5 proved it). Manual bf16 ushort ops.
// Dtype runtime-detection: flagI (edge_index int64 vs int32), flagF (floats
// fp32 vs packed bf16).
//
// R16: whole MLP (96->256->128->64->8) fused into ONE kernel. R15 ran it as
// 4 mfma dispatches: 4.5 GFLOP (~2us of MFMA) but ~90 MB of intermediate
// write+read traffic (bufB 25.6MB, bufA 12.8MB, bufC 6.4MB, x2) + 3 launch
// gaps. Now each wave owns 16 rows end-to-end; layer outputs live in
// wave-private LDS slices (no barriers: wave reads only what it wrote);
// strides 264/136/72 shorts keep bf16x8 LDS accesses 16B-aligned.
// GCN part (agg-then-gemm, partition-sort CSR) unchanged from R15.

#define GN 50000
#define GE 800000
#define NPART 98        // partitions of 512 dst nodes
#define PSLOT 9216      // slab capacity per partition (mean 8163, +11 sigma)
#define CHK 2048        // edges per block in pass 1

typedef __attribute__((ext_vector_type(8))) short bf16x8;
typedef __attribute__((ext_vector_type(4))) float floatx4;

__device__ __forceinline__ float ar1_b2f(unsigned short h) {
    return __uint_as_float(((unsigned)h) << 16);
}
__device__ __forceinline__ unsigned short ar1_f2b(float f) {
    unsigned u = __float_as_uint(f);
    u = u + 0x7FFFu + ((u >> 16) & 1u);   // round-to-nearest-even
    return (unsigned short)(u >> 16);
}

// block 0: flagI (edge_index int64 <=> odd words ~all zero) + zero gcur
// block 1: flagF (floats fp32 vs packed bf16; see R6 notes)
__global__ void ar1_detect(const int* ei, const unsigned short* xw,
                           int* flagI, int* flagF, int* gcur) {
    __shared__ int cnt;
    if (threadIdx.x == 0) cnt = 0;
    __syncthreads();
    if (blockIdx.x == 0) {
        if ((int)threadIdx.x < NPART) gcur[threadIdx.x] = 0;
        if (ei[2 * threadIdx.x + 1] != 0) atomicAdd(&cnt, 1);
        __syncthreads();
        if (threadIdx.x == 0) flagI[0] = (cnt < 8) ? 1 : 0;
    } else {
        unsigned short w = xw[2 * threadIdx.x];
        int ex = (w >> 7) & 0xFF;
        if (w == 0 || (ex >= 90 && ex <= 150)) atomicAdd(&cnt, 1);
        __syncthreads();
        if (threadIdx.x == 0) flagF[0] = (cnt > 200) ? 0 : 1;
    }
}

// pass 1: partition edges into 98 slabs; packed word = s | (d&511)<<17
__global__ __launch_bounds__(256)
void ar1_part(const int* __restrict__ ei, const int* __restrict__ flagI,
              int* __restrict__ gcur, unsigned int* __restrict__ pairs, int E) {
    __shared__ int cnt[NPART], base[NPART], cur[NPART];
    int tid = (int)threadIdx.x;
    for (int i = tid; i < NPART; i += 256) { cnt[i] = 0; cur[i] = 0; }
    __syncthreads();
    int is64 = flagI[0];
    int e0 = (int)blockIdx.x * CHK;
    unsigned pk[8]; int q[8];
#pragma unroll
    for (int k = 0; k < 8; k++) {
        int e = e0 + k * 256 + tid;
        q[k] = -1; pk[k] = 0;
        if (e < E) {
            int s = is64 ? ei[2 * e] : ei[e];
            int d = is64 ? ei[2 * (E + e)] : ei[E + e];
            if ((unsigned)s < (unsigned)GN && (unsigned)d < (unsigned)GN) {
                int qq = d >> 9;
                q[k] = qq;
                pk[k] = (unsigned)s | ((unsigned)(d & 511) << 17);
                atomicAdd(&cnt[qq], 1);
            }
        }
    }
    __syncthreads();
    for (int i = tid; i < NPART; i += 256)
        base[i] = (cnt[i] > 0) ? atomicAdd(&gcur[i], cnt[i]) : 0;
    __syncthreads();
#pragma unroll
    for (int k = 0; k < 8; k++) {
        if (q[k] >= 0) {
            int r = base[q[k]] + atomicAdd(&cur[q[k]], 1);
            if (r < PSLOT) pairs[(size_t)q[k] * PSLOT + r] = pk[k];
        }
    }
}

// exclusive scan of partition sizes -> global CSR base per partition
__global__ void ar1_pscan(const int* gcur, int* pbase) {
    __shared__ int sm[128];
    int tid = (int)threadIdx.x;   // 128
    int v = (tid < NPART) ? gcur[tid] : 0;
    sm[tid] = v;
    __syncthreads();
    for (int off = 1; off < 128; off <<= 1) {
        int t = (tid >= off) ? sm[tid - off] : 0;
        __syncthreads();
        sm[tid] += t;
        __syncthreads();
    }
    if (tid < NPART) pbase[tid] = sm[tid] - v;
}

// pass 2: per-partition -> contiguous CSR slice + indeg/offs/dinv
__global__ __launch_bounds__(256)
void ar1_csr(const unsigned int* __restrict__ pairs, const int* __restrict__ gcur,
             const int* __restrict__ pbase, int* __restrict__ csr,
             int* __restrict__ indeg, int* __restrict__ offs,
             float* __restrict__ dinv) {
    __shared__ int ncnt[512], pre[512], cur[512], psum[16];
    int p = (int)blockIdx.x, tid = (int)threadIdx.x;
    int cntE = gcur[p];
    if (cntE > PSLOT) cntE = PSLOT;
    int gbase = pbase[p];
    for (int i = tid; i < 512; i += 256) ncnt[i] = 0;
    __syncthreads();
    const unsigned int* pp = pairs + (size_t)p * PSLOT;
    for (int i = tid; i < cntE; i += 256) atomicAdd(&ncnt[pp[i] >> 17], 1);
    __syncthreads();
    if (tid < 16) {
        int s = 0;
        for (int j = tid * 32; j < tid * 32 + 32; j++) { pre[j] = s; s += ncnt[j]; }
        psum[tid] = s;
    }
    __syncthreads();
    if (tid == 0) {
        int s = 0;
        for (int j = 0; j < 16; j++) { int t = psum[j]; psum[j] = s; s += t; }
    }
    __syncthreads();
    if (tid < 16)
        for (int j = tid * 32; j < tid * 32 + 32; j++) pre[j] += psum[tid];
    __syncthreads();
    for (int j = tid; j < 512; j += 256) {
        cur[j] = pre[j];
        int node = p * 512 + j;
        if (node < GN) {
            indeg[node] = ncnt[j];
            offs[node] = gbase + pre[j];
            dinv[node] = rsqrtf((float)(ncnt[j] + 1));   // +1: self loop
        }
    }
    __syncthreads();
    for (int i = tid; i < cntE; i += 256) {
        unsigned v = pp[i];
        int r = atomicAdd(&cur[v >> 17], 1);
        csr[gbase + r] = (int)(v & 0x1FFFFu);
    }
}

// MLP biases -> fp32, plus GCN bias/BN fold: scale=C*g, shift=b*C*g+be
struct SmallCvt {
    const void* src[4];   // lb1, lb2, lb3, lb4
    float* dst[4];
    int n[4];
    const void* gb[9];    // b1,g1,be1, b2,g2,be2, b3,g3,be3
    float* ss[6];         // scale1,shift1, scale2,shift2, scale3,shift3
};
__global__ void ar1_cvt_small(SmallCvt sc, const int* flagF) {
    int f = flagF[0];
    const float C = 0.9999950000374997f;   // 1/sqrt(1+1e-5)
    for (int s = 0; s < 4; s++) {
        for (int i = threadIdx.x; i < sc.n[s]; i += 256) {
            float v = f ? ((const float*)sc.src[s])[i]
                        : ar1_b2f(((const unsigned short*)sc.src[s])[i]);
            sc.dst[s][i] = v;
        }
    }
    for (int k = 0; k < 3; k++) {
        for (int i = threadIdx.x; i < 96; i += 256) {
            float b, g, be;
            if (f) {
                b  = ((const float*)sc.gb[3 * k + 0])[i];
                g  = ((const float*)sc.gb[3 * k + 1])[i];
                be = ((const float*)sc.gb[3 * k + 2])[i];
            } else {
                b  = ar1_b2f(((const unsigned short*)sc.gb[3 * k + 0])[i]);
                g  = ar1_b2f(((const unsigned short*)sc.gb[3 * k + 1])[i]);
                be = ar1_b2f(((const unsigned short*)sc.gb[3 * k + 2])[i]);
            }
            sc.ss[2 * k + 0][i] = C * g;
            sc.ss[2 * k + 1][i] = b * C * g + be;
        }
    }
}

// fused pack of all 7 weights into MFMA B-fragment order (see R10 notes)
struct PackAll {
    const void* src[7];
    unsigned short* dst[7];
    int K[7], M[7], start[8];
};
__global__ void ar1_pack_all(PackAll pa, const int* flagF) {
    int b = (int)blockIdx.x;
    int w = 0;
    while (w < 6 && b >= pa.start[w + 1]) w++;
    int frag = b - pa.start[w];
    int K = pa.K[w], M = pa.M[w];
    int lane = (int)threadIdx.x;
    int nch = K >> 5;
    int t = frag / nch, c = frag - t * nch;
    int n = t * 16 + (lane & 15);
    int k0 = c * 32 + (lane >> 4) * 8;
    int f = flagF[0];
    unsigned short* o = pa.dst[w] + ((size_t)frag * 64 + lane) * 8;
    for (int j = 0; j < 8; j++) {
        unsigned short v = 0;
        if (n < M) {
            int idx = (k0 + j) * M + n;
            v = f ? ar1_f2b(((const float*)pa.src[w])[idx])
                  : ((const unsigned short*)pa.src[w])[idx];
        }
        o[j] = v;
    }
}

// ---------------- MFMA GEMM (GCN layers): C = A @ W, affine epilogue --------
template <int NT>
__global__ __launch_bounds__(256, 2)
void ar1_mfma(const unsigned short* __restrict__ A,
              const unsigned short* __restrict__ Bp,
              const float* __restrict__ scale, const float* __restrict__ shift,
              unsigned short* __restrict__ C, int K, int Astride, int Cstride,
              int Mout) {
    int tid = (int)threadIdx.x;
    int wv = tid >> 6, lane = tid & 63;
    int mb = ((int)blockIdx.x * 4 + wv) * 16;
    int m = lane & 15, quad = lane >> 4;
    int arow = mb + m;
    if (arow >= GN) arow = GN - 1;          // clamp; rows >= GN never stored
    const unsigned short* Aptr = A + (size_t)arow * Astride + quad * 8;
    int nch = K >> 5;

    floatx4 acc[NT];
#pragma unroll
    for (int t = 0; t < NT; t++) acc[t] = (floatx4){0.f, 0.f, 0.f, 0.f};

    for (int c = 0; c < nch; c++) {
        bf16x8 a = *((const bf16x8*)(Aptr + c * 32));
#pragma unroll
        for (int t = 0; t < NT; t++) {
            bf16x8 b = *((const bf16x8*)(Bp + ((size_t)(t * nch + c) * 64 + lane) * 8));
            acc[t] = __builtin_amdgcn_mfma_f32_16x16x32_bf16(a, b, acc[t], 0, 0, 0);
        }
    }

#pragma unroll
    for (int t = 0; t < NT; t++) {
#pragma unroll
        for (int r = 0; r < 4; r++) {
            int row = mb + quad * 4 + r;
            int col = t * 16 + m;
            if (row < GN && col < Mout) {
                float v = acc[t][r] * scale[col] + shift[col];
                C[(size_t)row * Cstride + col] = ar1_f2b(fmaxf(v, 0.f));
            }
        }
    }
}

// ---------------- fused MLP: 96->256->128->64->8, one kernel ---------------
// Wave owns 16 rows end-to-end; layer outputs in wave-private LDS slices
// (no barriers). Strides 264/136/72 shorts keep bf16x8 LDS reads 16B-aligned.
__global__ __launch_bounds__(256, 2)
void ar1_mlp(const unsigned short* __restrict__ A,
             const unsigned short* __restrict__ b3,
             const unsigned short* __restrict__ b4,
             const unsigned short* __restrict__ b5,
             const unsigned short* __restrict__ b6,
             const float* __restrict__ lb0, const float* __restrict__ lb1,
             const float* __restrict__ lb2, const float* __restrict__ lb3,
             void* __restrict__ out, const int* __restrict__ f32out) {
    __shared__ unsigned short H1[64 * 264];   // 256 cols
    __shared__ unsigned short H2[64 * 136];   // 128 cols
    __shared__ unsigned short H3[64 * 72];    // 64 cols
    int tid = (int)threadIdx.x, wv = tid >> 6, lane = tid & 63;
    int m = lane & 15, quad = lane >> 4;
    int mb = (int)blockIdx.x * 64 + wv * 16;
    int lwv = wv * 16;

    // ---- layer 1: 96 -> 256 (K=96, nch=3, NT=16) ----
    {
        int arow = mb + m; if (arow >= GN) arow = GN - 1;
        const unsigned short* Ap = A + (size_t)arow * 128 + quad * 8;
        floatx4 acc[16];
#pragma unroll
        for (int t = 0; t < 16; t++) acc[t] = (floatx4){0.f, 0.f, 0.f, 0.f};
        for (int c = 0; c < 3; c++) {
            bf16x8 a = *((const bf16x8*)(Ap + c * 32));
#pragma unroll
            for (int t = 0; t < 16; t++) {
                bf16x8 b = *((const bf16x8*)(b3 + ((size_t)(t * 3 + c) * 64 + lane) * 8));
                acc[t] = __builtin_amdgcn_mfma_f32_16x16x32_bf16(a, b, acc[t], 0, 0, 0);
            }
        }
#pragma unroll
        for (int t = 0; t < 16; t++)
#pragma unroll
            for (int r = 0; r < 4; r++) {
                int lr = lwv + quad * 4 + r, col = t * 16 + m;
                H1[lr * 264 + col] = ar1_f2b(fmaxf(acc[t][r] + lb0[col], 0.f));
            }
    }
    // ---- layer 2: 256 -> 128 (nch=8, NT=8) ----
    {
        const unsigned short* Hp = H1 + (size_t)(lwv + m) * 264 + quad * 8;
        floatx4 acc[8];
#pragma unroll
        for (int t = 0; t < 8; t++) acc[t] = (floatx4){0.f, 0.f, 0.f, 0.f};
        for (int c = 0; c < 8; c++) {
            bf16x8 a = *((const bf16x8*)(Hp + c * 32));
#pragma unroll
            for (int t = 0; t < 8; t++) {
                bf16x8 b = *((const bf16x8*)(b4 + ((size_t)(t * 8 + c) * 64 + lane) * 8));
                acc[t] = __builtin_amdgcn_mfma_f32_16x16x32_bf16(a, b, acc[t], 0, 0, 0);
            }
        }
#pragma unroll
        for (int t = 0; t < 8; t++)
#pragma unroll
            for (int r = 0; r < 4; r++) {
                int lr = lwv + quad * 4 + r, col = t * 16 + m;
                H2[lr * 136 + col] = ar1_f2b(fmaxf(acc[t][r] + lb1[col], 0.f));
            }
    }
    // ---- layer 3: 128 -> 64 (nch=4, NT=4) ----
    {
        const unsigned short* Hp = H2 + (size_t)(lwv + m) * 136 + quad * 8;
        floatx4 acc[4];
#pragma unroll
        for (int t = 0; t < 4; t++) acc[t] = (floatx4){0.f, 0.f, 0.f, 0.f};
        for (int c = 0; c < 4; c++) {
            bf16x8 a = *((const bf16x8*)(Hp + c * 32));
#pragma unroll
            for (int t = 0; t < 4; t++) {
                bf16x8 b = *((const bf16x8*)(b5 + ((size_t)(t * 4 + c) * 64 + lane) * 8));
                acc[t] = __builtin_amdgcn_mfma_f32_16x16x32_bf16(a, b, acc[t], 0, 0, 0);
            }
        }
#pragma unroll
        for (int t = 0; t < 4; t++)
#pragma unroll
            for (int r = 0; r < 4; r++) {
                int lr = lwv + quad * 4 + r, col = t * 16 + m;
                H3[lr * 72 + col] = ar1_f2b(fmaxf(acc[t][r] + lb2[col], 0.f));
            }
    }
    // ---- layer 4: 64 -> 8 (nch=2, NT=1, M padded 16) ----
    {
        const unsigned short* Hp = H3 + (size_t)(lwv + m) * 72 + quad * 8;
        floatx4 acc = (floatx4){0.f, 0.f, 0.f, 0.f};
        for (int c = 0; c < 2; c++) {
            bf16x8 a = *((const bf16x8*)(Hp + c * 32));
            bf16x8 b = *((const bf16x8*)(b6 + ((size_t)c * 64 + lane) * 8));
            acc = __builtin_amdgcn_mfma_f32_16x16x32_bf16(a, b, acc, 0, 0, 0);
        }
        int wf32 = f32out[0];
#pragma unroll
        for (int r = 0; r < 4; r++) {
            int row = mb + quad * 4 + r;
            if (row < GN && m < 8) {
                float v = acc[r] + lb3[m];
                if (wf32) ((float*)out)[(size_t)row * 8 + m] = v;
                else ((unsigned short*)out)[(size_t)row * 8 + m] = ar1_f2b(v);
            }
        }
    }
}

// ---------------- aggregate, 64-dim rows (layer 1, on x) --------------------
__global__ __launch_bounds__(256, 8)
void ar1_agg64(const unsigned short* __restrict__ X, const int* __restrict__ offs,
               const int* __restrict__ indeg, const int* __restrict__ csr,
               const float* __restrict__ dinv, unsigned short* __restrict__ Out) {
    int wv = (int)threadIdx.x >> 6, lane = (int)threadIdx.x & 63;
    int node = (int)blockIdx.x * 4 + wv;
    if (node >= GN) return;
    int chunk = lane & 7;      // feats chunk*8 .. +8
    int eslot = lane >> 3;     // 0..7
    float di = dinv[node];
    int off = offs[node], cnt = indeg[node];

    float acc[8];
#pragma unroll
    for (int j = 0; j < 8; j++) acc[j] = 0.f;

    for (int base = 0; base < cnt; base += 16) {
        int ss[2]; float ww[2];
#pragma unroll
        for (int k = 0; k < 2; k++) {
            int e = base + k * 8 + eslot;
            int s = node; float w = 0.f;
            if (e < cnt) {
                s = csr[off + e];
                if ((unsigned)s >= (unsigned)GN) s = node;
                w = dinv[s] * di;
            }
            ss[k] = s; ww[k] = w;
        }
        bf16x8 h0 = *((const bf16x8*)(X + (size_t)ss[0] * 64 + chunk * 8));
        bf16x8 h1 = *((const bf16x8*)(X + (size_t)ss[1] * 64 + chunk * 8));
#pragma unroll
        for (int j = 0; j < 8; j++)
            acc[j] += ww[0] * ar1_b2f((unsigned short)h0[j])
                    + ww[1] * ar1_b2f((unsigned short)h1[j]);
    }

#pragma unroll
    for (int j = 0; j < 8; j++) {
        acc[j] += __shfl_xor(acc[j], 8, 64);
        acc[j] += __shfl_xor(acc[j], 16, 64);
        acc[j] += __shfl_xor(acc[j], 32, 64);
    }

    if (eslot == 0) {
        bf16x8 hs = *((const bf16x8*)(X + (size_t)node * 64 + chunk * 8));
#pragma unroll
        for (int j = 0; j < 8; j++) {
            float v = acc[j] + di * di * ar1_b2f((unsigned short)hs[j]);
            Out[(size_t)node * 64 + chunk * 8 + j] = ar1_f2b(v);
        }
    }
}

// ---------------- aggregate, 96-dim rows padded 128 (layers 2,3) ------------
__global__ __launch_bounds__(256, 8)
void ar1_agg96(const unsigned short* __restrict__ H, const int* __restrict__ offs,
               const int* __restrict__ indeg, const int* __restrict__ csr,
               const float* __restrict__ dinv, unsigned short* __restrict__ Out) {
    int wv = (int)threadIdx.x >> 6, lane = (int)threadIdx.x & 63;
    int node = (int)blockIdx.x * 4 + wv;
    if (node >= GN) return;
    int chunk = lane & 15;
    int eslot = lane >> 4;
    float di = dinv[node];
    int off = offs[node], cnt = indeg[node];

    float acc[8];
#pragma unroll
    for (int j = 0; j < 8; j++) acc[j] = 0.f;

    for (int base = 0; base < cnt; base += 16) {
        int ss[4]; float ww[4]; bf16x8 hh[4];
#pragma unroll
        for (int k = 0; k < 4; k++) {
            int e = base + k * 4 + eslot;
            int s = node; float w = 0.f;
            if (e < cnt) {
                s = csr[off + e];
                if ((unsigned)s >= (unsigned)GN) s = node;
                w = dinv[s] * di;
            }
            ss[k] = s; ww[k] = w;
        }
#pragma unroll
        for (int k = 0; k < 4; k++)
            hh[k] = *((const bf16x8*)(H + (size_t)ss[k] * 128 + chunk * 8));
#pragma unroll
        for (int k = 0; k < 4; k++)
#pragma unroll
            for (int j = 0; j < 8; j++)
                acc[j] += ww[k] * ar1_b2f((unsigned short)hh[k][j]);
    }

#pragma unroll
    for (int j = 0; j < 8; j++) {
        acc[j] += __shfl_xor(acc[j], 16, 64);
        acc[j] += __shfl_xor(acc[j], 32, 64);
    }

    if (eslot == 0 && chunk < 12) {
        bf16x8 hs = *((const bf16x8*)(H + (size_t)node * 128 + chunk * 8));
#pragma unroll
        for (int j = 0; j < 8; j++) {
            float v = acc[j] + di * di * ar1_b2f((unsigned short)hs[j]);
            Out[(size_t)node * 128 + chunk * 8 + j] = ar1_f2b(v);
        }
    }
}

// x -> bf16 row-major (also carries the harness kernel name)
__global__ void Arthur1_16458314678864_kernel(const void* src,
                                              unsigned short* dst, int n,
                                              const int* flagF) {
    int i = blockIdx.x * 256 + threadIdx.x;
    if (i < n) {
        if (flagF[0]) dst[i] = ar1_f2b(((const float*)src)[i]);
        else          dst[i] = ((const unsigned short*)src)[i];
    }
}

extern "C" void kernel_launch(void* const* d_in, const int* in_sizes, int n_in,
                              void* d_out, int out_size, void* d_ws, size_t ws_size,
                              hipStream_t stream) {
    (void)in_sizes; (void)n_in; (void)out_size;

    // workspace layout
    char* p = (char*)d_ws;
    unsigned short* bufA = (unsigned short*)p; p += (size_t)GN * 128 * 2;  // 12.8 MB
    unsigned short* bufC = (unsigned short*)p; p += (size_t)GN * 128 * 2;  // 12.8 MB
    unsigned short* bufX = (unsigned short*)p; p += (size_t)GN * 64 * 2;   // 6.4 MB
    unsigned int* pairs = (unsigned int*)p; p += (size_t)NPART * PSLOT * 4; // 3.6 MB
    int* indeg  = (int*)p;    p += (size_t)GN * 4;
    int* offs   = (int*)p;    p += (size_t)GN * 4;
    float* dinv = (float*)p;  p += (size_t)GN * 4;
    int* csr    = (int*)p;    p += (size_t)GE * 4;
    int* gcur   = (int*)p;    p += 1024;
    int* pbase  = (int*)p;    p += 1024;
    int* flagI  = (int*)p;    p += 1024;
    int* flagF  = (int*)p;    p += 1024;
    unsigned short* bpArena = (unsigned short*)p; p += 91136 * 2;  // packed W
    float* fArena = (float*)p; p += 2048 * 4;                      // small fp32
    size_t need = (size_t)(p - (char*)d_ws);
    if (ws_size < need) {
        hipMemsetAsync(d_out, 0x41, (size_t)GN * 8 * 2, stream);  // marker 12.06
        return;
    }

    // packed-weight arena offsets (shorts): w1,w2,w3,lw1,lw2,lw3,lw4
    unsigned short* bp[7];
    int bpn[7] = {6144, 9216, 9216, 24576, 32768, 8192, 1024};
    {
        unsigned short* q = bpArena;
        for (int i = 0; i < 7; i++) { bp[i] = q; q += bpn[i]; }
    }

    // small fp32 arena: lb1(256),lb2(128),lb3(64),lb4(8), 6 x 96 scale/shift
    float* lb[4]; float* ss[6];
    {
        float* q = fArena;
        int ln[4] = {256, 128, 64, 8};
        for (int i = 0; i < 4; i++) { lb[i] = q; q += ln[i]; }
        for (int i = 0; i < 6; i++) { ss[i] = q; q += 96; }
    }

    const int* ei = (const int*)d_in[1];

    // graph build (partition sort)
    ar1_detect<<<2, 256, 0, stream>>>(ei, (const unsigned short*)d_in[0], flagI, flagF, gcur);
    ar1_part<<<(GE + CHK - 1) / CHK, 256, 0, stream>>>(ei, flagI, gcur, pairs, GE);
    ar1_pscan<<<1, 128, 0, stream>>>(gcur, pbase);
    ar1_csr<<<NPART, 256, 0, stream>>>(pairs, gcur, pbase, csr, indeg, offs, dinv);

    // conversions
    Arthur1_16458314678864_kernel<<<(GN * 64 + 255) / 256, 256, 0, stream>>>(
        d_in[0], bufX, GN * 64, flagF);
    {
        SmallCvt sc;
        int lsrc[4] = {15, 17, 19, 21};
        int ln[4] = {256, 128, 64, 8};
        for (int i = 0; i < 4; i++) { sc.src[i] = d_in[lsrc[i]]; sc.dst[i] = lb[i]; sc.n[i] = ln[i]; }
        int gsrc[9] = {3, 4, 5, 7, 8, 9, 11, 12, 13};
        for (int i = 0; i < 9; i++) sc.gb[i] = d_in[gsrc[i]];
        for (int i = 0; i < 6; i++) sc.ss[i] = ss[i];
        ar1_cvt_small<<<1, 256, 0, stream>>>(sc, flagF);
    }
    {
        PackAll pa;
        int wsrc[7] = {2, 6, 10, 14, 16, 18, 20};
        int Ks[7] = {64, 96, 96, 96, 256, 128, 64};
        int Ms[7] = {96, 96, 96, 256, 128, 64, 8};
        int cum = 0;
        for (int i = 0; i < 7; i++) {
            pa.src[i] = d_in[wsrc[i]]; pa.dst[i] = bp[i];
            pa.K[i] = Ks[i]; pa.M[i] = Ms[i];
            pa.start[i] = cum;
            cum += (Ms[i] + 15) / 16 * (Ks[i] / 32);
        }
        pa.start[7] = cum;   // 178
        ar1_pack_all<<<cum, 64, 0, stream>>>(pa, flagF);
    }

    const int GB = (GN + 63) / 64;    // 64 rows per block
    const int AB = GN / 4;            // agg: 4 nodes per block (12500 exact)

    // GCN 1..3: aggregate first (linearity), then GEMM with affine epilogue
    ar1_agg64<<<AB, 256, 0, stream>>>(bufX, offs, indeg, csr, dinv, bufC);
    ar1_mfma<6><<<GB, 256, 0, stream>>>(bufC, bp[0], ss[0], ss[1], bufA, 64, 64, 128, 96);
    ar1_agg96<<<AB, 256, 0, stream>>>(bufA, offs, indeg, csr, dinv, bufC);
    ar1_mfma<6><<<GB, 256, 0, stream>>>(bufC, bp[1], ss[2], ss[3], bufA, 96, 128, 128, 96);
    ar1_agg96<<<AB, 256, 0, stream>>>(bufA, offs, indeg, csr, dinv, bufC);
    ar1_mfma<6><<<GB, 256, 0, stream>>>(bufC, bp[2], ss[4], ss[5], bufA, 96, 128, 128, 96);

    // fused MLP: 96->256->128->64->8, writes d_out (fp32/bf16 per flagF)
    ar1_mlp<<<GB, 256, 0, stream>>>(bufA, bp[3], bp[4], bp[5], bp[6],
                                    lb[0], lb[1], lb[2], lb[3], d_out, flagF);
}

// Round 17
// 324.709 us; speedup vs baseline: 1.8927x; 1.0209x over previous
//
#include <hip/hip_runtime.h>

// GCN(3 layers) + MLP(4 layers), N=50000, E=800000, out = N x 8 bf16.
// NOTE: do NOT include <hip/hip_bf16.h> — breaks this harness's build
// (rounds 1-4 fell back to a stub; round 5 proved it). Manual bf16 ushort ops.
// Dtype runtime-detection: flagI (edge_index int64 vs int32), flagF (floats
// fp32 vs packed bf16).
//
// R17: (a) drop the 96->128 row padding. 96 bf16 = 192 B = exactly 3 cache
// lines, 64B-aligned at stride 96 — the pad cost a 4th line per gathered
// edge (agg96 FETCH 83.8 MB vs ~63 MB demand). agg96 remapped to 4 eslots x
// 12 chunks (48 active lanes; bytes beat lanes in a miss-bound gather);
// reduce via dynamic __shfl. (b) agg64 reads d_in[0] directly (uniform
// flagF branch) — cvt_x copy kernel deleted. (c) pack_all + cvt_small fused
// into one launch. GCN agg->gemm order, partition-sort CSR, fused MLP kept.

#define GN 50000
#define GE 800000
#define NPART 98        // partitions of 512 dst nodes
#define PSLOT 9216      // slab capacity per partition (mean 8163, +11 sigma)
#define CHK 2048        // edges per block in pass 1

typedef __attribute__((ext_vector_type(8))) short bf16x8;
typedef __attribute__((ext_vector_type(4))) float floatx4;

__device__ __forceinline__ float ar1_b2f(unsigned short h) {
    return __uint_as_float(((unsigned)h) << 16);
}
__device__ __forceinline__ unsigned short ar1_f2b(float f) {
    unsigned u = __float_as_uint(f);
    u = u + 0x7FFFu + ((u >> 16) & 1u);   // round-to-nearest-even
    return (unsigned short)(u >> 16);
}

// block 0: flagI (edge_index int64 <=> odd words ~all zero) + zero gcur
// block 1: flagF (floats fp32 vs packed bf16; see R6 notes)
__global__ void ar1_detect(const int* ei, const unsigned short* xw,
                           int* flagI, int* flagF, int* gcur) {
    __shared__ int cnt;
    if (threadIdx.x == 0) cnt = 0;
    __syncthreads();
    if (blockIdx.x == 0) {
        if ((int)threadIdx.x < NPART) gcur[threadIdx.x] = 0;
        if (ei[2 * threadIdx.x + 1] != 0) atomicAdd(&cnt, 1);
        __syncthreads();
        if (threadIdx.x == 0) flagI[0] = (cnt < 8) ? 1 : 0;
    } else {
        unsigned short w = xw[2 * threadIdx.x];
        int ex = (w >> 7) & 0xFF;
        if (w == 0 || (ex >= 90 && ex <= 150)) atomicAdd(&cnt, 1);
        __syncthreads();
        if (threadIdx.x == 0) flagF[0] = (cnt > 200) ? 0 : 1;
    }
}

// pass 1: partition edges into 98 slabs; packed word = s | (d&511)<<17
__global__ __launch_bounds__(256)
void ar1_part(const int* __restrict__ ei, const int* __restrict__ flagI,
              int* __restrict__ gcur, unsigned int* __restrict__ pairs, int E) {
    __shared__ int cnt[NPART], base[NPART], cur[NPART];
    int tid = (int)threadIdx.x;
    for (int i = tid; i < NPART; i += 256) { cnt[i] = 0; cur[i] = 0; }
    __syncthreads();
    int is64 = flagI[0];
    int e0 = (int)blockIdx.x * CHK;
    unsigned pk[8]; int q[8];
#pragma unroll
    for (int k = 0; k < 8; k++) {
        int e = e0 + k * 256 + tid;
        q[k] = -1; pk[k] = 0;
        if (e < E) {
            int s = is64 ? ei[2 * e] : ei[e];
            int d = is64 ? ei[2 * (E + e)] : ei[E + e];
            if ((unsigned)s < (unsigned)GN && (unsigned)d < (unsigned)GN) {
                int qq = d >> 9;
                q[k] = qq;
                pk[k] = (unsigned)s | ((unsigned)(d & 511) << 17);
                atomicAdd(&cnt[qq], 1);
            }
        }
    }
    __syncthreads();
    for (int i = tid; i < NPART; i += 256)
        base[i] = (cnt[i] > 0) ? atomicAdd(&gcur[i], cnt[i]) : 0;
    __syncthreads();
#pragma unroll
    for (int k = 0; k < 8; k++) {
        if (q[k] >= 0) {
            int r = base[q[k]] + atomicAdd(&cur[q[k]], 1);
            if (r < PSLOT) pairs[(size_t)q[k] * PSLOT + r] = pk[k];
        }
    }
}

// exclusive scan of partition sizes -> global CSR base per partition
__global__ void ar1_pscan(const int* gcur, int* pbase) {
    __shared__ int sm[128];
    int tid = (int)threadIdx.x;   // 128
    int v = (tid < NPART) ? gcur[tid] : 0;
    sm[tid] = v;
    __syncthreads();
    for (int off = 1; off < 128; off <<= 1) {
        int t = (tid >= off) ? sm[tid - off] : 0;
        __syncthreads();
        sm[tid] += t;
        __syncthreads();
    }
    if (tid < NPART) pbase[tid] = sm[tid] - v;
}

// pass 2: per-partition -> contiguous CSR slice + indeg/offs/dinv
__global__ __launch_bounds__(256)
void ar1_csr(const unsigned int* __restrict__ pairs, const int* __restrict__ gcur,
             const int* __restrict__ pbase, int* __restrict__ csr,
             int* __restrict__ indeg, int* __restrict__ offs,
             float* __restrict__ dinv) {
    __shared__ int ncnt[512], pre[512], cur[512], psum[16];
    int p = (int)blockIdx.x, tid = (int)threadIdx.x;
    int cntE = gcur[p];
    if (cntE > PSLOT) cntE = PSLOT;
    int gbase = pbase[p];
    for (int i = tid; i < 512; i += 256) ncnt[i] = 0;
    __syncthreads();
    const unsigned int* pp = pairs + (size_t)p * PSLOT;
    for (int i = tid; i < cntE; i += 256) atomicAdd(&ncnt[pp[i] >> 17], 1);
    __syncthreads();
    if (tid < 16) {
        int s = 0;
        for (int j = tid * 32; j < tid * 32 + 32; j++) { pre[j] = s; s += ncnt[j]; }
        psum[tid] = s;
    }
    __syncthreads();
    if (tid == 0) {
        int s = 0;
        for (int j = 0; j < 16; j++) { int t = psum[j]; psum[j] = s; s += t; }
    }
    __syncthreads();
    if (tid < 16)
        for (int j = tid * 32; j < tid * 32 + 32; j++) pre[j] += psum[tid];
    __syncthreads();
    for (int j = tid; j < 512; j += 256) {
        cur[j] = pre[j];
        int node = p * 512 + j;
        if (node < GN) {
            indeg[node] = ncnt[j];
            offs[node] = gbase + pre[j];
            dinv[node] = rsqrtf((float)(ncnt[j] + 1));   // +1: self loop
        }
    }
    __syncthreads();
    for (int i = tid; i < cntE; i += 256) {
        unsigned v = pp[i];
        int r = atomicAdd(&cur[v >> 17], 1);
        csr[gbase + r] = (int)(v & 0x1FFFFu);
    }
}

struct PackAll {
    const void* src[7];
    unsigned short* dst[7];
    int K[7], M[7], start[8];
};
struct SmallCvt {
    const void* src[4];   // lb1, lb2, lb3, lb4
    float* dst[4];
    int n[4];
    const void* gb[9];    // b1,g1,be1, b2,g2,be2, b3,g3,be3
    float* ss[6];         // scale1,shift1, ...
};

// fused weight prep (carries the harness kernel name):
// blocks 0..44: pack 4 fragments each into MFMA B order (178 frags total);
// block 45: small-vector cvt + GCN bias/BN fold (scale=C*g, shift=b*C*g+be).
__global__ void Arthur1_16458314678864_kernel(PackAll pa, SmallCvt sc,
                                              const int* flagF) {
    int b = (int)blockIdx.x;
    int f = flagF[0];
    if (b < 45) {
        int frag_g = b * 4 + ((int)threadIdx.x >> 6);
        if (frag_g >= 178) return;
        int w = 0;
        while (w < 6 && frag_g >= pa.start[w + 1]) w++;
        int frag = frag_g - pa.start[w];
        int K = pa.K[w], M = pa.M[w];
        int lane = (int)threadIdx.x & 63;
        int nch = K >> 5;
        int t = frag / nch, c = frag - t * nch;
        int n = t * 16 + (lane & 15);
        int k0 = c * 32 + (lane >> 4) * 8;
        unsigned short* o = pa.dst[w] + ((size_t)frag * 64 + lane) * 8;
        for (int j = 0; j < 8; j++) {
            unsigned short v = 0;
            if (n < M) {
                int idx = (k0 + j) * M + n;
                v = f ? ar1_f2b(((const float*)pa.src[w])[idx])
                      : ((const unsigned short*)pa.src[w])[idx];
            }
            o[j] = v;
        }
    } else {
        const float C = 0.9999950000374997f;   // 1/sqrt(1+1e-5)
        for (int s = 0; s < 4; s++) {
            for (int i = threadIdx.x; i < sc.n[s]; i += 256) {
                float v = f ? ((const float*)sc.src[s])[i]
                            : ar1_b2f(((const unsigned short*)sc.src[s])[i]);
                sc.dst[s][i] = v;
            }
        }
        for (int k = 0; k < 3; k++) {
            for (int i = threadIdx.x; i < 96; i += 256) {
                float bb, g, be;
                if (f) {
                    bb = ((const float*)sc.gb[3 * k + 0])[i];
                    g  = ((const float*)sc.gb[3 * k + 1])[i];
                    be = ((const float*)sc.gb[3 * k + 2])[i];
                } else {
                    bb = ar1_b2f(((const unsigned short*)sc.gb[3 * k + 0])[i]);
                    g  = ar1_b2f(((const unsigned short*)sc.gb[3 * k + 1])[i]);
                    be = ar1_b2f(((const unsigned short*)sc.gb[3 * k + 2])[i]);
                }
                sc.ss[2 * k + 0][i] = C * g;
                sc.ss[2 * k + 1][i] = bb * C * g + be;
            }
        }
    }
}

// ---------------- MFMA GEMM (GCN layers): C = A @ W, affine+ReLU epilogue ---
// A bf16 rows (Astride shorts); C bf16 rows (Cstride shorts), Mout=96 (NT=6).
template <int NT>
__global__ __launch_bounds__(256, 2)
void ar1_mfma(const unsigned short* __restrict__ A,
              const unsigned short* __restrict__ Bp,
              const float* __restrict__ scale, const float* __restrict__ shift,
              unsigned short* __restrict__ C, int K, int Astride, int Cstride) {
    int tid = (int)threadIdx.x;
    int wv = tid >> 6, lane = tid & 63;
    int mb = ((int)blockIdx.x * 4 + wv) * 16;
    int m = lane & 15, quad = lane >> 4;
    int arow = mb + m;
    if (arow >= GN) arow = GN - 1;          // clamp; rows >= GN never stored
    const unsigned short* Aptr = A + (size_t)arow * Astride + quad * 8;
    int nch = K >> 5;

    floatx4 acc[NT];
#pragma unroll
    for (int t = 0; t < NT; t++) acc[t] = (floatx4){0.f, 0.f, 0.f, 0.f};

    for (int c = 0; c < nch; c++) {
        bf16x8 a = *((const bf16x8*)(Aptr + c * 32));
#pragma unroll
        for (int t = 0; t < NT; t++) {
            bf16x8 b = *((const bf16x8*)(Bp + ((size_t)(t * nch + c) * 64 + lane) * 8));
            acc[t] = __builtin_amdgcn_mfma_f32_16x16x32_bf16(a, b, acc[t], 0, 0, 0);
        }
    }

#pragma unroll
    for (int t = 0; t < NT; t++) {
#pragma unroll
        for (int r = 0; r < 4; r++) {
            int row = mb + quad * 4 + r;
            int col = t * 16 + m;
            if (row < GN) {
                float v = acc[t][r] * scale[col] + shift[col];
                C[(size_t)row * Cstride + col] = ar1_f2b(fmaxf(v, 0.f));
            }
        }
    }
}

// ---------------- fused MLP: 96->256->128->64->8, one kernel ---------------
// Wave owns 16 rows end-to-end; layer outputs in wave-private LDS slices
// (no barriers). A rows stride 96.
__global__ __launch_bounds__(256, 2)
void ar1_mlp(const unsigned short* __restrict__ A,
             const unsigned short* __restrict__ b3,
             const unsigned short* __restrict__ b4,
             const unsigned short* __restrict__ b5,
             const unsigned short* __restrict__ b6,
             const float* __restrict__ lb0, const float* __restrict__ lb1,
             const float* __restrict__ lb2, const float* __restrict__ lb3,
             void* __restrict__ out, const int* __restrict__ f32out) {
    __shared__ unsigned short H1[64 * 264];   // 256 cols
    __shared__ unsigned short H2[64 * 136];   // 128 cols
    __shared__ unsigned short H3[64 * 72];    // 64 cols
    int tid = (int)threadIdx.x, wv = tid >> 6, lane = tid & 63;
    int m = lane & 15, quad = lane >> 4;
    int mb = (int)blockIdx.x * 64 + wv * 16;
    int lwv = wv * 16;

    // ---- layer 1: 96 -> 256 (nch=3, NT=16) ----
    {
        int arow = mb + m; if (arow >= GN) arow = GN - 1;
        const unsigned short* Ap = A + (size_t)arow * 96 + quad * 8;
        floatx4 acc[16];
#pragma unroll
        for (int t = 0; t < 16; t++) acc[t] = (floatx4){0.f, 0.f, 0.f, 0.f};
        for (int c = 0; c < 3; c++) {
            bf16x8 a = *((const bf16x8*)(Ap + c * 32));
#pragma unroll
            for (int t = 0; t < 16; t++) {
                bf16x8 b = *((const bf16x8*)(b3 + ((size_t)(t * 3 + c) * 64 + lane) * 8));
                acc[t] = __builtin_amdgcn_mfma_f32_16x16x32_bf16(a, b, acc[t], 0, 0, 0);
            }
        }
#pragma unroll
        for (int t = 0; t < 16; t++)
#pragma unroll
            for (int r = 0; r < 4; r++) {
                int lr = lwv + quad * 4 + r, col = t * 16 + m;
                H1[lr * 264 + col] = ar1_f2b(fmaxf(acc[t][r] + lb0[col], 0.f));
            }
    }
    // ---- layer 2: 256 -> 128 (nch=8, NT=8) ----
    {
        const unsigned short* Hp = H1 + (size_t)(lwv + m) * 264 + quad * 8;
        floatx4 acc[8];
#pragma unroll
        for (int t = 0; t < 8; t++) acc[t] = (floatx4){0.f, 0.f, 0.f, 0.f};
        for (int c = 0; c < 8; c++) {
            bf16x8 a = *((const bf16x8*)(Hp + c * 32));
#pragma unroll
            for (int t = 0; t < 8; t++) {
                bf16x8 b = *((const bf16x8*)(b4 + ((size_t)(t * 8 + c) * 64 + lane) * 8));
                acc[t] = __builtin_amdgcn_mfma_f32_16x16x32_bf16(a, b, acc[t], 0, 0, 0);
            }
        }
#pragma unroll
        for (int t = 0; t < 8; t++)
#pragma unroll
            for (int r = 0; r < 4; r++) {
                int lr = lwv + quad * 4 + r, col = t * 16 + m;
                H2[lr * 136 + col] = ar1_f2b(fmaxf(acc[t][r] + lb1[col], 0.f));
            }
    }
    // ---- layer 3: 128 -> 64 (nch=4, NT=4) ----
    {
        const unsigned short* Hp = H2 + (size_t)(lwv + m) * 136 + quad * 8;
        floatx4 acc[4];
#pragma unroll
        for (int t = 0; t < 4; t++) acc[t] = (floatx4){0.f, 0.f, 0.f, 0.f};
        for (int c = 0; c < 4; c++) {
            bf16x8 a = *((const bf16x8*)(Hp + c * 32));
#pragma unroll
            for (int t = 0; t < 4; t++) {
                bf16x8 b = *((const bf16x8*)(b5 + ((size_t)(t * 4 + c) * 64 + lane) * 8));
                acc[t] = __builtin_amdgcn_mfma_f32_16x16x32_bf16(a, b, acc[t], 0, 0, 0);
            }
        }
#pragma unroll
        for (int t = 0; t < 4; t++)
#pragma unroll
            for (int r = 0; r < 4; r++) {
                int lr = lwv + quad * 4 + r, col = t * 16 + m;
                H3[lr * 72 + col] = ar1_f2b(fmaxf(acc[t][r] + lb2[col], 0.f));
            }
    }
    // ---- layer 4: 64 -> 8 (nch=2, NT=1, M padded 16) ----
    {
        const unsigned short* Hp = H3 + (size_t)(lwv + m) * 72 + quad * 8;
        floatx4 acc = (floatx4){0.f, 0.f, 0.f, 0.f};
        for (int c = 0; c < 2; c++) {
            bf16x8 a = *((const bf16x8*)(Hp + c * 32));
            bf16x8 b = *((const bf16x8*)(b6 + ((size_t)c * 64 + lane) * 8));
            acc = __builtin_amdgcn_mfma_f32_16x16x32_bf16(a, b, acc, 0, 0, 0);
        }
        int wf32 = f32out[0];
#pragma unroll
        for (int r = 0; r < 4; r++) {
            int row = mb + quad * 4 + r;
            if (row < GN && m < 8) {
                float v = acc[r] + lb3[m];
                if (wf32) ((float*)out)[(size_t)row * 8 + m] = v;
                else ((unsigned short*)out)[(size_t)row * 8 + m] = ar1_f2b(v);
            }
        }
    }
}

// ---------------- aggregate over x (64-dim), reading d_in[0] directly ------
// lane = eslot(3b) x chunk(3b); 2x unroll. Uniform flagF branch per load.
__global__ __launch_bounds__(256, 8)
void ar1_agg64(const void* __restrict__ Xv, const int* __restrict__ offs,
               const int* __restrict__ indeg, const int* __restrict__ csr,
               const float* __restrict__ dinv, const int* __restrict__ flagF,
               unsigned short* __restrict__ Out) {
    int wv = (int)threadIdx.x >> 6, lane = (int)threadIdx.x & 63;
    int node = (int)blockIdx.x * 4 + wv;
    if (node >= GN) return;
    int chunk = lane & 7;      // feats chunk*8 .. +8
    int eslot = lane >> 3;     // 0..7
    float di = dinv[node];
    int off = offs[node], cnt = indeg[node];
    int f = flagF[0];
    const unsigned short* X16 = (const unsigned short*)Xv;
    const float* X32 = (const float*)Xv;

    float acc[8];
#pragma unroll
    for (int j = 0; j < 8; j++) acc[j] = 0.f;

    for (int base = 0; base < cnt; base += 16) {
        int ss[2]; float ww[2];
#pragma unroll
        for (int k = 0; k < 2; k++) {
            int e = base + k * 8 + eslot;
            int s = node; float w = 0.f;
            if (e < cnt) {
                s = csr[off + e];
                if ((unsigned)s >= (unsigned)GN) s = node;
                w = dinv[s] * di;
            }
            ss[k] = s; ww[k] = w;
        }
#pragma unroll
        for (int k = 0; k < 2; k++) {
            float hv[8];
            if (f) {
                floatx4 a = *((const floatx4*)(X32 + (size_t)ss[k] * 64 + chunk * 8));
                floatx4 b = *((const floatx4*)(X32 + (size_t)ss[k] * 64 + chunk * 8 + 4));
#pragma unroll
                for (int j = 0; j < 4; j++) { hv[j] = a[j]; hv[4 + j] = b[j]; }
            } else {
                bf16x8 h = *((const bf16x8*)(X16 + (size_t)ss[k] * 64 + chunk * 8));
#pragma unroll
                for (int j = 0; j < 8; j++) hv[j] = ar1_b2f((unsigned short)h[j]);
            }
#pragma unroll
            for (int j = 0; j < 8; j++) acc[j] += ww[k] * hv[j];
        }
    }

#pragma unroll
    for (int j = 0; j < 8; j++) {
        acc[j] += __shfl_xor(acc[j], 8, 64);
        acc[j] += __shfl_xor(acc[j], 16, 64);
        acc[j] += __shfl_xor(acc[j], 32, 64);
    }

    if (eslot == 0) {
        float hv[8];
        if (f) {
            floatx4 a = *((const floatx4*)(X32 + (size_t)node * 64 + chunk * 8));
            floatx4 b = *((const floatx4*)(X32 + (size_t)node * 64 + chunk * 8 + 4));
#pragma unroll
            for (int j = 0; j < 4; j++) { hv[j] = a[j]; hv[4 + j] = b[j]; }
        } else {
            bf16x8 h = *((const bf16x8*)(X16 + (size_t)node * 64 + chunk * 8));
#pragma unroll
            for (int j = 0; j < 8; j++) hv[j] = ar1_b2f((unsigned short)h[j]);
        }
#pragma unroll
        for (int j = 0; j < 8; j++) {
            float v = acc[j] + di * di * hv[j];
            Out[(size_t)node * 64 + chunk * 8 + j] = ar1_f2b(v);
        }
    }
}

// ---------------- aggregate, 96-dim rows, stride 96 (layers 2,3) ------------
// 192 B rows = 3 cache lines, 64B-aligned. 4 eslots x 12 chunks (48 active
// lanes); 4x edge unroll; dynamic-shfl reduce; self-loop fused.
__global__ __launch_bounds__(256, 8)
void ar1_agg96(const unsigned short* __restrict__ H, const int* __restrict__ offs,
               const int* __restrict__ indeg, const int* __restrict__ csr,
               const float* __restrict__ dinv, unsigned short* __restrict__ Out) {
    int wv = (int)threadIdx.x >> 6, lane = (int)threadIdx.x & 63;
    int node = (int)blockIdx.x * 4 + wv;
    if (node >= GN) return;
    int chunk = lane % 12;     // feats chunk*8 .. +8
    int eslot = lane / 12;     // 0..3 active; 5 (lanes 60-63) idle too
    int active = (lane < 48) ? 1 : 0;
    float di = dinv[node];
    int off = offs[node], cnt = indeg[node];

    float acc[8];
#pragma unroll
    for (int j = 0; j < 8; j++) acc[j] = 0.f;

    if (active) {
        for (int base = 0; base < cnt; base += 16) {
            int ss[4]; float ww[4]; bf16x8 hh[4];
#pragma unroll
            for (int k = 0; k < 4; k++) {
                int e = base + k * 4 + eslot;
                int s = node; float w = 0.f;
                if (e < cnt) {
                    s = csr[off + e];
                    if ((unsigned)s >= (unsigned)GN) s = node;
                    w = dinv[s] * di;
                }
                ss[k] = s; ww[k] = w;
            }
#pragma unroll
            for (int k = 0; k < 4; k++)
                hh[k] = *((const bf16x8*)(H + (size_t)ss[k] * 96 + chunk * 8));
#pragma unroll
            for (int k = 0; k < 4; k++)
#pragma unroll
                for (int j = 0; j < 8; j++)
                    acc[j] += ww[k] * ar1_b2f((unsigned short)hh[k][j]);
        }
    }

    // sum partials: writer lane c needs lanes {c, c+12, c+24, c+36}
#pragma unroll
    for (int j = 0; j < 8; j++) {
        float a1 = __shfl(acc[j], lane + 12, 64);
        float a2 = __shfl(acc[j], lane + 24, 64);
        float a3 = __shfl(acc[j], lane + 36, 64);
        acc[j] += a1 + a2 + a3;
    }

    if (lane < 12) {
        bf16x8 hs = *((const bf16x8*)(H + (size_t)node * 96 + chunk * 8));
#pragma unroll
        for (int j = 0; j < 8; j++) {
            float v = acc[j] + di * di * ar1_b2f((unsigned short)hs[j]);
            Out[(size_t)node * 96 + chunk * 8 + j] = ar1_f2b(v);
        }
    }
}

extern "C" void kernel_launch(void* const* d_in, const int* in_sizes, int n_in,
                              void* d_out, int out_size, void* d_ws, size_t ws_size,
                              hipStream_t stream) {
    (void)in_sizes; (void)n_in; (void)out_size;

    // workspace layout
    char* p = (char*)d_ws;
    unsigned short* bufA = (unsigned short*)p; p += (size_t)GN * 96 * 2;   // 9.6 MB
    unsigned short* bufC = (unsigned short*)p; p += (size_t)GN * 96 * 2;   // 9.6 MB
    unsigned int* pairs = (unsigned int*)p; p += (size_t)NPART * PSLOT * 4; // 3.6 MB
    int* indeg  = (int*)p;    p += (size_t)GN * 4;
    int* offs   = (int*)p;    p += (size_t)GN * 4;
    float* dinv = (float*)p;  p += (size_t)GN * 4;
    int* csr    = (int*)p;    p += (size_t)GE * 4;
    int* gcur   = (int*)p;    p += 1024;
    int* pbase  = (int*)p;    p += 1024;
    int* flagI  = (int*)p;    p += 1024;
    int* flagF  = (int*)p;    p += 1024;
    unsigned short* bpArena = (unsigned short*)p; p += 91136 * 2;  // packed W
    float* fArena = (float*)p; p += 2048 * 4;                      // small fp32
    size_t need = (size_t)(p - (char*)d_ws);
    if (ws_size < need) {
        hipMemsetAsync(d_out, 0x41, (size_t)GN * 8 * 2, stream);  // marker 12.06
        return;
    }

    // packed-weight arena offsets (shorts): w1,w2,w3,lw1,lw2,lw3,lw4
    unsigned short* bp[7];
    int bpn[7] = {6144, 9216, 9216, 24576, 32768, 8192, 1024};
    {
        unsigned short* q = bpArena;
        for (int i = 0; i < 7; i++) { bp[i] = q; q += bpn[i]; }
    }

    // small fp32 arena: lb1(256),lb2(128),lb3(64),lb4(8), 6 x 96 scale/shift
    float* lb[4]; float* ss[6];
    {
        float* q = fArena;
        int ln[4] = {256, 128, 64, 8};
        for (int i = 0; i < 4; i++) { lb[i] = q; q += ln[i]; }
        for (int i = 0; i < 6; i++) { ss[i] = q; q += 96; }
    }

    const int* ei = (const int*)d_in[1];

    // graph build (partition sort)
    ar1_detect<<<2, 256, 0, stream>>>(ei, (const unsigned short*)d_in[0], flagI, flagF, gcur);
    ar1_part<<<(GE + CHK - 1) / CHK, 256, 0, stream>>>(ei, flagI, gcur, pairs, GE);
    ar1_pscan<<<1, 128, 0, stream>>>(gcur, pbase);
    ar1_csr<<<NPART, 256, 0, stream>>>(pairs, gcur, pbase, csr, indeg, offs, dinv);

    // fused weight prep (pack 178 frags + small cvt/fold)
    {
        PackAll pa;
        int wsrc[7] = {2, 6, 10, 14, 16, 18, 20};
        int Ks[7] = {64, 96, 96, 96, 256, 128, 64};
        int Ms[7] = {96, 96, 96, 256, 128, 64, 8};
        int cum = 0;
        for (int i = 0; i < 7; i++) {
            pa.src[i] = d_in[wsrc[i]]; pa.dst[i] = bp[i];
            pa.K[i] = Ks[i]; pa.M[i] = Ms[i];
            pa.start[i] = cum;
            cum += (Ms[i] + 15) / 16 * (Ks[i] / 32);
        }
        pa.start[7] = cum;   // 178
        SmallCvt sc;
        int lsrc[4] = {15, 17, 19, 21};
        int ln[4] = {256, 128, 64, 8};
        for (int i = 0; i < 4; i++) { sc.src[i] = d_in[lsrc[i]]; sc.dst[i] = lb[i]; sc.n[i] = ln[i]; }
        int gsrc[9] = {3, 4, 5, 7, 8, 9, 11, 12, 13};
        for (int i = 0; i < 9; i++) sc.gb[i] = d_in[gsrc[i]];
        for (int i = 0; i < 6; i++) sc.ss[i] = ss[i];
        Arthur1_16458314678864_kernel<<<46, 256, 0, stream>>>(pa, sc, flagF);
    }

    const int GB = (GN + 63) / 64;    // 64 rows per block
    const int AB = GN / 4;            // agg: 4 nodes per block (12500 exact)

    // GCN 1..3: aggregate first (linearity), then GEMM with affine epilogue
    ar1_agg64<<<AB, 256, 0, stream>>>(d_in[0], offs, indeg, csr, dinv, flagF, bufC);
    ar1_mfma<6><<<GB, 256, 0, stream>>>(bufC, bp[0], ss[0], ss[1], bufA, 64, 64, 96);
    ar1_agg96<<<AB, 256, 0, stream>>>(bufA, offs, indeg, csr, dinv, bufC);
    ar1_mfma<6><<<GB, 256, 0, stream>>>(bufC, bp[1], ss[2], ss[3], bufA, 96, 96, 96);
    ar1_agg96<<<AB, 256, 0, stream>>>(bufA, offs, indeg, csr, dinv, bufC);
    ar1_mfma<6><<<GB, 256, 0, stream>>>(bufC, bp[2], ss[4], ss[5], bufA, 96, 96, 96);

    // fused MLP: 96->256->128->64->8, writes d_out (fp32/bf16 per flagF)
    ar1_mlp<<<GB, 256, 0, stream>>>(bufA, bp[3], bp[4], bp[5], bp[6],
                                    lb[0], lb[1], lb[2], lb[3], d_out, flagF);
}